// Round 12
// baseline (454.901 us; speedup 1.0000x reference)
//
#include <hip/hip_runtime.h>

// ---------------------------------------------------------------------------
// Fused multimodal net: l-MLP + 2 LSTMs (MFMA bf16, LDS-staged) + tiny
// transformer head. N=4096, T=256, DA=74, DV=47, hidden=32.
//
// LSTM kernel: MODALITY-FUSED blocks for in-stream ILP. Block = 128 threads
// = 2 waves, handling a-group [n0,n0+16) AND v-group [n0,n0+16) (256 blocks,
// 1024 waves chip-wide = 1/SIMD — grid-capped occupancy, so latency must be
// hidden *within* the stream: the two independent recurrences interleave).
// Per combined step: {h-reads a,v} -> {produce gx_a[t+1] (12 MFMA),
// gx_v[t+1] (8 MFMA)} -> {consume a: 4 h-MFMA + trans; consume v: same} ->
// one shared barrier. Row map (r8-verified): gate row G = r*32 + wid*16 +
// q*4 + T; lane (q,c) C-regs 0..3 = i,f,g,o of unit wid*16+q*4+T; lane's 4
// h values contiguous => 2 cvt_pk + 1 ds_write_b64. h via ping-pong LDS.
// x staged via global_load_lds, 4-slot ring per modality (prefetch dist 3),
// alternating-wave turns, vmcnt(0) drain one step after issue (counted
// discipline: at most own stages outstanding). Weight zeros beyond D carry
// x tail masking; LDS over-reads land in staged/zeroed regions (finite).
// ---------------------------------------------------------------------------

typedef float float4v __attribute__((ext_vector_type(4)));
typedef float float2v __attribute__((ext_vector_type(2)));
typedef short short8v __attribute__((ext_vector_type(8)));
typedef unsigned uint2v __attribute__((ext_vector_type(2)));

#define N_SAMPLES 4096
#define T_STEPS 256
#define DA 74
#define DV 47
#define FPSA (16 * DA)  // 1184 floats per a-slot
#define FPSV (16 * DV)  // 752 floats per v-slot
#define HSTR 40         // shorts per sample row in H
#define HB 640          // shorts per H buffer (16*40)

#define LGKM0 asm volatile("s_waitcnt lgkmcnt(0)" ::: "memory")
#define VM0 asm volatile("s_waitcnt vmcnt(0)" ::: "memory")

__device__ __forceinline__ short bf16r(float f) {
  unsigned u = __float_as_uint(f);
  u += 0x7FFFu + ((u >> 16) & 1u);
  return (short)(u >> 16);
}
__device__ __forceinline__ unsigned cvt_pk_bf16(float lo, float hi) {
  unsigned r;
  asm("v_cvt_pk_bf16_f32 %0, %1, %2" : "=v"(r) : "v"(lo), "v"(hi));
  return r;
}
__device__ __forceinline__ float sigm_(float x) {
  return __builtin_amdgcn_rcpf(1.0f +
                               __builtin_amdgcn_exp2f(x * -1.44269504f));
}
__device__ __forceinline__ float tanh_(float x) {
  return 1.0f - 2.0f * __builtin_amdgcn_rcpf(
                           1.0f + __builtin_amdgcn_exp2f(x * 2.88539009f));
}
__device__ __forceinline__ float4v mfma32(short8v a, short8v b, float4v c) {
  return __builtin_amdgcn_mfma_f32_16x16x32_bf16(a, b, c, 0, 0, 0);
}
__device__ __forceinline__ void gld16(const float* g, float* l) {
  __builtin_amdgcn_global_load_lds(
      (const __attribute__((address_space(1))) unsigned int*)g,
      (__attribute__((address_space(3))) unsigned int*)l, 16, 0, 0);
}

// LDS: xa 4*1184*4=18944 | xv 4*752*4=12032 | Hua 2560 | Huv 2560 | = 36096
#define XA_OFF 0
#define XV_OFF 18944
#define HUA_OFF (18944 + 12032)
#define HUV_OFF (HUA_OFF + 2560)
#define SMEM_BYTES (HUV_OFF + 2560 + 64)

__global__ __launch_bounds__(128, 1) void lstm_both(
    const float* __restrict__ a, const float* __restrict__ v,
    const float* __restrict__ aWih, const float* __restrict__ aWhh,
    const float* __restrict__ abih, const float* __restrict__ abhh,
    const float* __restrict__ aWo, const float* __restrict__ abo,
    const float* __restrict__ vWih, const float* __restrict__ vWhh,
    const float* __restrict__ vbih, const float* __restrict__ vbhh,
    const float* __restrict__ vWo, const float* __restrict__ vbo,
    float* __restrict__ afw, float* __restrict__ vfw) {
  __shared__ __align__(16) char smem[SMEM_BYTES];
  float* xa = (float*)(smem + XA_OFF);
  float* xv = (float*)(smem + XV_OFF);
  unsigned short* Hua = (unsigned short*)(smem + HUA_OFF);
  unsigned short* Huv = (unsigned short*)(smem + HUV_OFF);

  const int n0 = blockIdx.x * 16;
  const int tid = threadIdx.x;
  const int wid = tid >> 6;
  const int lane = tid & 63;
  const int c = lane & 15;
  const int q = lane >> 4;

  auto stageA = [&](int t) {
    const float* gs = a + (size_t)t * (N_SAMPLES * DA) + (size_t)n0 * DA;
    float* ls = xa + (t & 3) * FPSA;
#pragma unroll
    for (int r = 0; r < 4; ++r) gld16(gs + (r * 64 + lane) * 4, ls + r * 256);
    if (lane < 40) gld16(gs + (256 + lane) * 4, ls + 1024);
  };
  auto stageV = [&](int t) {
    const float* gs = v + (size_t)t * (N_SAMPLES * DV) + (size_t)n0 * DV;
    float* ls = xv + (t & 3) * FPSV;
#pragma unroll
    for (int r = 0; r < 2; ++r) gld16(gs + (r * 64 + lane) * 4, ls + r * 256);
    if (lane < 60) gld16(gs + (128 + lane) * 4, ls + 512);
  };

  // prologue staging: wave0 -> slots 0,2 ; wave1 -> slot 1 (both rings)
  if (wid == 0) { stageA(0); stageV(0); stageA(2); stageV(2); }
  else          { stageA(1); stageV(1); }

  // stationary weights: BOTH modalities, 4 tiles (16 units) per wave each.
  const int G = (c & 3) * 32 + wid * 16 + (c >> 2) * 4;  // + T
  short8v wax[4][3], wah[4], wvx[4][2], wvh[4];
  float4v bina[4], binv[4];
#pragma unroll
  for (int T = 0; T < 4; ++T) {
    const float* wr = aWih + (G + T) * DA;
#pragma unroll
    for (int kt = 0; kt < 3; ++kt) {
      short8v s;
#pragma unroll
      for (int e = 0; e < 8; ++e) {
        const int d = kt * 32 + q * 8 + e;
        s[e] = (d < DA) ? bf16r(wr[d]) : (short)0;
      }
      wax[T][kt] = s;
    }
    const float* hr = aWhh + (G + T) * 32;
#pragma unroll
    for (int e = 0; e < 8; ++e) wah[T][e] = bf16r(hr[q * 8 + e]);
    const float* wrv = vWih + (G + T) * DV;
#pragma unroll
    for (int kt = 0; kt < 2; ++kt) {
      short8v s;
#pragma unroll
      for (int e = 0; e < 8; ++e) {
        const int d = kt * 32 + q * 8 + e;
        s[e] = (d < DV) ? bf16r(wrv[d]) : (short)0;
      }
      wvx[T][kt] = s;
    }
    const float* hrv = vWhh + (G + T) * 32;
#pragma unroll
    for (int e = 0; e < 8; ++e) wvh[T][e] = bf16r(hrv[q * 8 + e]);
#pragma unroll
    for (int r = 0; r < 4; ++r) {
      const int Gr = r * 32 + wid * 16 + q * 4 + T;
      bina[T][r] = abih[Gr] + abhh[Gr];
      binv[T][r] = vbih[Gr] + vbhh[Gr];
    }
  }

  {  // zero both H regions (5120 B = 1280 dwords)
    unsigned* Hz = (unsigned*)Hua;
    for (int i = tid; i < 1280; i += 128) Hz[i] = 0;
  }

  VM0;    // own prologue stages landed
  LGKM0;  // H zeros visible
  __builtin_amdgcn_s_barrier();

  auto ldcvtA = [&](int slot, short8v* xo) {
    const float* xs = xa + slot * FPSA + c * DA;
#pragma unroll
    for (int kt = 0; kt < 3; ++kt) {
      const float* p = xs + kt * 32 + q * 8;
      const float2v r0 = *(const float2v*)(p);
      const float2v r1 = *(const float2v*)(p + 2);
      const float2v r2 = *(const float2v*)(p + 4);
      const float2v r3 = *(const float2v*)(p + 6);
      union { short8v s; unsigned u[4]; } fr;
      fr.u[0] = cvt_pk_bf16(r0[0], r0[1]);
      fr.u[1] = cvt_pk_bf16(r1[0], r1[1]);
      fr.u[2] = cvt_pk_bf16(r2[0], r2[1]);
      fr.u[3] = cvt_pk_bf16(r3[0], r3[1]);
      xo[kt] = fr.s;
    }
  };
  auto ldcvtV = [&](int slot, short8v* xo) {
    const float* xs = xv + slot * FPSV + c * DV;
#pragma unroll
    for (int kt = 0; kt < 2; ++kt) {
      const float* p = xs + kt * 32 + q * 8;
      const float2v r0 = *(const float2v*)(p);
      const float2v r1 = *(const float2v*)(p + 2);
      const float2v r2 = *(const float2v*)(p + 4);
      const float2v r3 = *(const float2v*)(p + 6);
      union { short8v s; unsigned u[4]; } fr;
      fr.u[0] = cvt_pk_bf16(r0[0], r0[1]);
      fr.u[1] = cvt_pk_bf16(r1[0], r1[1]);
      fr.u[2] = cvt_pk_bf16(r2[0], r2[1]);
      fr.u[3] = cvt_pk_bf16(r3[0], r3[1]);
      xo[kt] = fr.s;
    }
  };

  float csta[4] = {0.0f, 0.0f, 0.0f, 0.0f};
  float cstv[4] = {0.0f, 0.0f, 0.0f, 0.0f};
  float4v gaA[4], gaB[4], gvA[4], gvB[4];
  {
    short8v xF[3];
    ldcvtA(0, xF);
#pragma unroll
    for (int T = 0; T < 4; ++T) {
      float4v g4 = bina[T];
#pragma unroll
      for (int kt = 0; kt < 3; ++kt) g4 = mfma32(wax[T][kt], xF[kt], g4);
      gaA[T] = g4;
    }
    short8v xG[2];
    ldcvtV(0, xG);
#pragma unroll
    for (int T = 0; T < 4; ++T) {
      float4v g4 = binv[T];
#pragma unroll
      for (int kt = 0; kt < 2; ++kt) g4 = mfma32(wvx[T][kt], xG[kt], g4);
      gvA[T] = g4;
    }
  }

  // one combined step (a-substep + v-substep), i = t&3 compile-time.
  auto STEP = [&](int t, int i, float4v (&gac)[4], float4v (&gan)[4],
                  float4v (&gvc)[4], float4v (&gvn)[4]) {
    const int pb = i & 1;
    // on-chain: h of step t-1, both modalities
    const short8v hBa = *(const short8v*)(Hua + pb * HB + c * HSTR + q * 8);
    const short8v hBv = *(const short8v*)(Huv + pb * HB + c * HSTR + q * 8);
    // staging: slot (t+3)&3 by wave (i+3)&1, both rings
    if (((i + 3) & 1) == wid && t + 3 < T_STEPS) { stageA(t + 3); stageV(t + 3); }
    // off-chain: x[t+1] frags + production, both modalities
    short8v xN[3];
    ldcvtA((i + 1) & 3, xN);
#pragma unroll
    for (int T = 0; T < 4; ++T) {
      float4v g4 = bina[T];
#pragma unroll
      for (int kt = 0; kt < 3; ++kt) g4 = mfma32(wax[T][kt], xN[kt], g4);
      gan[T] = g4;
    }
    short8v xM[2];
    ldcvtV((i + 1) & 3, xM);
#pragma unroll
    for (int T = 0; T < 4; ++T) {
      float4v g4 = binv[T];
#pragma unroll
      for (int kt = 0; kt < 2; ++kt) g4 = mfma32(wvx[T][kt], xM[kt], g4);
      gvn[T] = g4;
    }
    // on-chain consumers (independent chains interleave)
    __builtin_amdgcn_s_setprio(1);
    float hva[4], hvv[4];
#pragma unroll
    for (int T = 0; T < 4; ++T) {
      const float4v acc = mfma32(wah[T], hBa, gac[T]);
      const float iv = sigm_(acc[0]);
      const float fv = sigm_(acc[1]);
      const float gv = tanh_(acc[2]);
      const float ov = sigm_(acc[3]);
      const float cv = fv * csta[T] + iv * gv;
      csta[T] = cv;
      hva[T] = ov * tanh_(cv);
    }
#pragma unroll
    for (int T = 0; T < 4; ++T) {
      const float4v acc = mfma32(wvh[T], hBv, gvc[T]);
      const float iv = sigm_(acc[0]);
      const float fv = sigm_(acc[1]);
      const float gv = tanh_(acc[2]);
      const float ov = sigm_(acc[3]);
      const float cv = fv * cstv[T] + iv * gv;
      cstv[T] = cv;
      hvv[T] = ov * tanh_(cv);
    }
    uint2v hpa, hpv;
    hpa[0] = cvt_pk_bf16(hva[0], hva[1]);
    hpa[1] = cvt_pk_bf16(hva[2], hva[3]);
    hpv[0] = cvt_pk_bf16(hvv[0], hvv[1]);
    hpv[1] = cvt_pk_bf16(hvv[2], hvv[3]);
    *(uint2v*)(Hua + (1 - pb) * HB + c * HSTR + wid * 16 + q * 4) = hpa;
    *(uint2v*)(Huv + (1 - pb) * HB + c * HSTR + wid * 16 + q * 4) = hpv;
    __builtin_amdgcn_s_setprio(0);
    LGKM0;                          // h writes drained
    if ((i & 1) == wid) { VM0; }    // drain own stages (issued last step)
    __builtin_amdgcn_s_barrier();
  };

  for (int tb = 0; tb < T_STEPS; tb += 4) {
    STEP(tb + 0, 0, gaA, gaB, gvA, gvB);
    STEP(tb + 1, 1, gaB, gaA, gvB, gvA);
    STEP(tb + 2, 2, gaA, gaB, gvA, gvB);
    STEP(tb + 3, 3, gaB, gaA, gvB, gvA);
  }

  // epilogue: h[255] in buffer 0 for both; out = relu(h @ Wo^T + bo)
  {
    const short8v hBa = *(const short8v*)(Hua + c * HSTR + q * 8);
    const float* wor = aWo + (16 * wid + c) * 32;
    short8v w8;
#pragma unroll
    for (int e = 0; e < 8; ++e) w8[e] = bf16r(wor[q * 8 + e]);
    float4v o4 = {0.0f, 0.0f, 0.0f, 0.0f};
    o4 = mfma32(w8, hBa, o4);
    float4v res;
#pragma unroll
    for (int r = 0; r < 4; ++r)
      res[r] = fmaxf(o4[r] + abo[16 * wid + q * 4 + r], 0.0f);
    *(float4v*)(afw + (size_t)(n0 + c) * 32 + 16 * wid + q * 4) = res;
  }
  {
    const short8v hBv = *(const short8v*)(Huv + c * HSTR + q * 8);
    const float* wor = vWo + (16 * wid + c) * 32;
    short8v w8;
#pragma unroll
    for (int e = 0; e < 8; ++e) w8[e] = bf16r(wor[q * 8 + e]);
    float4v o4 = {0.0f, 0.0f, 0.0f, 0.0f};
    o4 = mfma32(w8, hBv, o4);
    float4v res;
#pragma unroll
    for (int r = 0; r < 4; ++r)
      res[r] = fmaxf(o4[r] + vbo[16 * wid + q * 4 + r], 0.0f);
    *(float4v*)(vfw + (size_t)(n0 + c) * 32 + 16 * wid + q * 4) = res;
  }
}

// ---------------------------------------------------------------------------
// lf = relu(relu(l @ lW1^T + lb1) @ lW2^T + lb2)   [4096,768]->[4096,32]
// ---------------------------------------------------------------------------
__global__ __launch_bounds__(256) void lf_kernel(
    const float* __restrict__ l, const float* __restrict__ lW1,
    const float* __restrict__ lb1, const float* __restrict__ lW2,
    const float* __restrict__ lb2, float* __restrict__ lf) {
  __shared__ __align__(16) float lsh[16 * 768];
  __shared__ __align__(16) float h1sh[16 * 128];
  const int tid = threadIdx.x;
  const int n0 = blockIdx.x * 16;

  {
    const float4v* src = (const float4v*)(l + (size_t)n0 * 768);
    float4v* dst = (float4v*)lsh;
#pragma unroll
    for (int i = 0; i < 12; ++i) dst[tid + i * 256] = src[tid + i * 256];
  }
  __syncthreads();

  {
    const int u = tid & 127;
    const int sg = tid >> 7;
    float acc[8];
#pragma unroll
    for (int i = 0; i < 8; ++i) acc[i] = 0.0f;
    const float4v* wrow = (const float4v*)(lW1 + u * 768);
    for (int k4 = 0; k4 < 192; ++k4) {
      const float4v w = wrow[k4];
#pragma unroll
      for (int i = 0; i < 8; ++i) {
        const float4v xv = ((const float4v*)(lsh + (sg * 8 + i) * 768))[k4];
        acc[i] += w[0] * xv[0] + w[1] * xv[1] + w[2] * xv[2] + w[3] * xv[3];
      }
    }
    const float b = lb1[u];
#pragma unroll
    for (int i = 0; i < 8; ++i)
      h1sh[(sg * 8 + i) * 128 + u] = fmaxf(acc[i] + b, 0.0f);
  }
  __syncthreads();

  {
    const int u2 = tid & 31;
    const int sg2 = tid >> 5;
    float acc0 = 0.0f, acc1 = 0.0f;
    const float4v* w2 = (const float4v*)(lW2 + u2 * 128);
#pragma unroll
    for (int k4 = 0; k4 < 32; ++k4) {
      const float4v w = w2[k4];
      const float4v xa = ((const float4v*)(h1sh + sg2 * 128))[k4];
      const float4v xb = ((const float4v*)(h1sh + (sg2 + 8) * 128))[k4];
      acc0 += w[0] * xa[0] + w[1] * xa[1] + w[2] * xa[2] + w[3] * xa[3];
      acc1 += w[0] * xb[0] + w[1] * xb[1] + w[2] * xb[2] + w[3] * xb[3];
    }
    const float b2 = lb2[u2];
    lf[(size_t)(n0 + sg2) * 32 + u2] = fmaxf(acc0 + b2, 0.0f);
    lf[(size_t)(n0 + sg2 + 8) * 32 + u2] = fmaxf(acc1 + b2, 0.0f);
  }
}

// ---------------------------------------------------------------------------
// Transformer block + post-fusion head. 32 lanes/sample, 8 samples/block.
// ---------------------------------------------------------------------------
__global__ __launch_bounds__(256) void head_kernel(
    const float* __restrict__ lf, const float* __restrict__ af,
    const float* __restrict__ vf, const float* __restrict__ Wq,
    const float* __restrict__ bq, const float* __restrict__ Wk,
    const float* __restrict__ bk, const float* __restrict__ Wv,
    const float* __restrict__ bv, const float* __restrict__ Wz,
    const float* __restrict__ bz, const float* __restrict__ Wff,
    const float* __restrict__ bff, const float* __restrict__ g1,
    const float* __restrict__ be1, const float* __restrict__ g2,
    const float* __restrict__ be2, const float* __restrict__ Wp1,
    const float* __restrict__ bp1, const float* __restrict__ Wp2,
    const float* __restrict__ bp2, float* __restrict__ out) {
  __shared__ float shA[8][3][33];
  __shared__ float shB[8][3][33];
  const int tid = threadIdx.x;
  const int j = tid & 31;
  const int slot = tid >> 5;
  const int n = blockIdx.x * 8 + slot;
  const size_t off = (size_t)n * 32 + j;

  const float x0 = lf[off], x1 = af[off], x2 = vf[off];

  auto ln3 = [&](float a0, float a1, float a2, const float* g,
                 const float* be, float* o) {
    float s = a0 + a1 + a2;
    s += __shfl_xor(s, 1); s += __shfl_xor(s, 2); s += __shfl_xor(s, 4);
    s += __shfl_xor(s, 8); s += __shfl_xor(s, 16);
    const float mu = s * (1.0f / 96.0f);
    const float d0 = a0 - mu, d1 = a1 - mu, d2 = a2 - mu;
    float ss = d0 * d0 + d1 * d1 + d2 * d2;
    ss += __shfl_xor(ss, 1); ss += __shfl_xor(ss, 2); ss += __shfl_xor(ss, 4);
    ss += __shfl_xor(ss, 8); ss += __shfl_xor(ss, 16);
    const float rs = rsqrtf(ss * (1.0f / 96.0f) + 1e-5f);
    o[0] = d0 * rs * g[j] + be[j];
    o[1] = d1 * rs * g[32 + j] + be[32 + j];
    o[2] = d2 * rs * g[64 + j] + be[64 + j];
  };

  float z[3];
  ln3(x0, x1, x2, g1, be1, z);
  shA[slot][0][j] = z[0]; shA[slot][1][j] = z[1]; shA[slot][2][j] = z[2];
  __syncthreads();

  float qv[3], kv[3], vv[3];
  {
    const float bqj = bq[j], bkj = bk[j], bvj = bv[j];
    qv[0] = bqj; qv[1] = bqj; qv[2] = bqj;
    kv[0] = bkj; kv[1] = bkj; kv[2] = bkj;
    vv[0] = bvj; vv[1] = bvj; vv[2] = bvj;
    const float* wqr = Wq + j * 32;
    const float* wkr = Wk + j * 32;
    const float* wvr = Wv + j * 32;
#pragma unroll 8
    for (int k = 0; k < 32; ++k) {
      const float zz0 = shA[slot][0][k], zz1 = shA[slot][1][k],
                  zz2 = shA[slot][2][k];
      const float wq = wqr[k], wk_ = wkr[k], wv_ = wvr[k];
      qv[0] += wq * zz0;  qv[1] += wq * zz1;  qv[2] += wq * zz2;
      kv[0] += wk_ * zz0; kv[1] += wk_ * zz1; kv[2] += wk_ * zz2;
      vv[0] += wv_ * zz0; vv[1] += wv_ * zz1; vv[2] += wv_ * zz2;
    }
  }

  float at[3][3];
#pragma unroll
  for (int s = 0; s < 3; ++s)
#pragma unroll
    for (int t2 = 0; t2 < 3; ++t2) {
      float p = qv[s] * kv[t2];
      p += __shfl_xor(p, 1); p += __shfl_xor(p, 2); p += __shfl_xor(p, 4);
      at[s][t2] = p;
    }
#pragma unroll
  for (int s = 0; s < 3; ++s) {
    const float m = fmaxf(fmaxf(at[s][0], at[s][1]), at[s][2]);
    const float e0 = __expf(at[s][0] - m), e1 = __expf(at[s][1] - m),
                e2 = __expf(at[s][2] - m);
    const float sc = 0.35355339059327373f * __fdividef(1.0f, e0 + e1 + e2);
    at[s][0] = e0 * sc; at[s][1] = e1 * sc; at[s][2] = e2 * sc;
  }
  float zc[3];
#pragma unroll
  for (int s = 0; s < 3; ++s)
    zc[s] = at[s][0] * vv[0] + at[s][1] * vv[1] + at[s][2] * vv[2];
  shB[slot][0][j] = zc[0]; shB[slot][1][j] = zc[1]; shB[slot][2][j] = zc[2];
  __syncthreads();

  const float bzj = bz[j];
  float z2a[3] = {bzj + x0, bzj + x1, bzj + x2};
  {
    const float* wzr = Wz + j * 32;
#pragma unroll 8
    for (int k = 0; k < 32; ++k) {
      const float w = wzr[k];
      z2a[0] += w * shB[slot][0][k];
      z2a[1] += w * shB[slot][1][k];
      z2a[2] += w * shB[slot][2][k];
    }
  }

  float zn[3];
  ln3(z2a[0], z2a[1], z2a[2], g2, be2, zn);
  shA[slot][0][j] = zn[0]; shA[slot][1][j] = zn[1]; shA[slot][2][j] = zn[2];
  __syncthreads();

  const float bffj = bff[j];
  float Za[3] = {bffj + z2a[0], bffj + z2a[1], bffj + z2a[2]};
  {
    const float* wfr = Wff + j * 32;
#pragma unroll 8
    for (int k = 0; k < 32; ++k) {
      const float w = wfr[k];
      Za[0] += w * shA[slot][0][k];
      Za[1] += w * shA[slot][1][k];
      Za[2] += w * shA[slot][2][k];
    }
  }
  shB[slot][0][j] = Za[0]; shB[slot][1][j] = Za[1]; shB[slot][2][j] = Za[2];
  __syncthreads();

  float p = bp1[j];
  {
    const float* wpr = Wp1 + j * 96;
#pragma unroll
    for (int s = 0; s < 3; ++s)
#pragma unroll 8
      for (int k = 0; k < 32; ++k) p += wpr[s * 32 + k] * shB[slot][s][k];
  }
  p = fmaxf(p, 0.0f);
  float l0 = Wp2[j] * p, l1 = Wp2[32 + j] * p;
  l0 += __shfl_xor(l0, 1); l0 += __shfl_xor(l0, 2); l0 += __shfl_xor(l0, 4);
  l0 += __shfl_xor(l0, 8); l0 += __shfl_xor(l0, 16);
  l1 += __shfl_xor(l1, 1); l1 += __shfl_xor(l1, 2); l1 += __shfl_xor(l1, 4);
  l1 += __shfl_xor(l1, 8); l1 += __shfl_xor(l1, 16);
  l0 += bp2[0]; l1 += bp2[1];
  const float mx = fmaxf(l0, l1);
  const float e0 = __expf(l0 - mx), e1 = __expf(l1 - mx);
  const float inv = __fdividef(1.0f, e0 + e1);
  if (j == 0) {
    out[(size_t)n * 2 + 0] = e0 * inv;
    out[(size_t)n * 2 + 1] = e1 * inv;
  }
}

// ---------------------------------------------------------------------------
extern "C" void kernel_launch(void* const* d_in, const int* in_sizes, int n_in,
                              void* d_out, int out_size, void* d_ws,
                              size_t ws_size, hipStream_t stream) {
  const float* l    = (const float*)d_in[0];
  const float* a    = (const float*)d_in[1];
  const float* v    = (const float*)d_in[2];
  const float* lW1  = (const float*)d_in[3];
  const float* lb1  = (const float*)d_in[4];
  const float* lW2  = (const float*)d_in[5];
  const float* lb2  = (const float*)d_in[6];
  const float* aWih = (const float*)d_in[7];
  const float* aWhh = (const float*)d_in[8];
  const float* abih = (const float*)d_in[9];
  const float* abhh = (const float*)d_in[10];
  const float* aWo  = (const float*)d_in[11];
  const float* abo  = (const float*)d_in[12];
  const float* vWih = (const float*)d_in[13];
  const float* vWhh = (const float*)d_in[14];
  const float* vbih = (const float*)d_in[15];
  const float* vbhh = (const float*)d_in[16];
  const float* vWo  = (const float*)d_in[17];
  const float* vbo  = (const float*)d_in[18];
  const float* Wq   = (const float*)d_in[19];
  const float* bq   = (const float*)d_in[20];
  const float* Wk   = (const float*)d_in[21];
  const float* bk   = (const float*)d_in[22];
  const float* Wv   = (const float*)d_in[23];
  const float* bv   = (const float*)d_in[24];
  const float* Wz   = (const float*)d_in[25];
  const float* bz   = (const float*)d_in[26];
  const float* Wff  = (const float*)d_in[27];
  const float* bff  = (const float*)d_in[28];
  const float* g1   = (const float*)d_in[29];
  const float* be1  = (const float*)d_in[30];
  const float* g2   = (const float*)d_in[31];
  const float* be2  = (const float*)d_in[32];
  const float* Wp1  = (const float*)d_in[33];
  const float* bp1  = (const float*)d_in[34];
  const float* Wp2  = (const float*)d_in[35];
  const float* bp2  = (const float*)d_in[36];

  float* out = (float*)d_out;
  float* ws = (float*)d_ws;
  float* lfw = ws;
  float* afw = ws + 4096 * 32;
  float* vfw = ws + 2 * 4096 * 32;

  hipLaunchKernelGGL(lstm_both, dim3(256), dim3(128), 0, stream, a, v, aWih,
                     aWhh, abih, abhh, aWo, abo, vWih, vWhh, vbih, vbhh, vWo,
                     vbo, afw, vfw);
  hipLaunchKernelGGL(lf_kernel, dim3(256), dim3(256), 0, stream, l, lW1, lb1,
                     lW2, lb2, lfw);
  hipLaunchKernelGGL(head_kernel, dim3(512), dim3(256), 0, stream, lfw, afw,
                     vfw, Wq, bq, Wk, bk, Wv, bv, Wz, bz, Wff, bff, g1, be1,
                     g2, be2, Wp1, bp1, Wp2, bp2, out);
}

// Round 13
// 277.283 us; speedup vs baseline: 1.6406x; 1.6406x over previous
//
#include <hip/hip_runtime.h>

// ---------------------------------------------------------------------------
// Fused multimodal net: [lf-MLP + 2 LSTMs] in ONE launch + transformer head.
// N=4096, T=256, DA=74, DV=47, hidden=32.
//
// Front kernel grid = 1024 blocks x 128 threads, 28.7KB LDS => exactly
// 4 blocks/CU, ALL co-resident: blocks 0-511 = lf-MLP (8 samples each),
// 512-767 = a-LSTM groups, 768-1023 = v-LSTM groups. lf's serial ~12us
// disappears under the LSTM wall.
//
// LSTM structure (r11 champion, measured 262us): 2 waves per 16-sample
// group. Row map: gate row G = r*32 + wid*16 + q*4 + T -> lane (q,c) C-regs
// 0..3 = i,f,g,o of unit wid*16+q*4+T; lane's 4 h values contiguous =>
// 2 cvt_pk + 1 ds_write_b64; h via ping-pong LDS, 1 barrier/step.
// Producer ring: step t produces gx[t+1] = bias + Wih@x[t+1] (off-chain
// MFMAs); on-chain: 1 ds_read_b128 (h) + 4 h-MFMAs + lean trans + b64 write.
// x staged via global_load_lds 4-slot ring (prefetch distance 3), even slots
// wave0 / odd wave1, stager drains vmcnt(0) one step after issue.
// ---------------------------------------------------------------------------

typedef float float4v __attribute__((ext_vector_type(4)));
typedef float float2v __attribute__((ext_vector_type(2)));
typedef short short8v __attribute__((ext_vector_type(8)));
typedef unsigned uint2v __attribute__((ext_vector_type(2)));

#define N_SAMPLES 4096
#define T_STEPS 256
#define HSTR 40           // shorts per sample row in H (32 units + pad)
#define HBUF (16 * HSTR)  // shorts per H buffer

#define LGKM0 asm volatile("s_waitcnt lgkmcnt(0)" ::: "memory")
#define VM0 asm volatile("s_waitcnt vmcnt(0)" ::: "memory")

__device__ __forceinline__ short bf16r(float f) {
  unsigned u = __float_as_uint(f);
  u += 0x7FFFu + ((u >> 16) & 1u);
  return (short)(u >> 16);
}
__device__ __forceinline__ unsigned cvt_pk_bf16(float lo, float hi) {
  unsigned r;
  asm("v_cvt_pk_bf16_f32 %0, %1, %2" : "=v"(r) : "v"(lo), "v"(hi));
  return r;
}
__device__ __forceinline__ float sigm_(float x) {
  return __builtin_amdgcn_rcpf(1.0f +
                               __builtin_amdgcn_exp2f(x * -1.44269504f));
}
__device__ __forceinline__ float tanh_(float x) {
  return 1.0f - 2.0f * __builtin_amdgcn_rcpf(
                           1.0f + __builtin_amdgcn_exp2f(x * 2.88539009f));
}
__device__ __forceinline__ float4v mfma32(short8v a, short8v b, float4v c) {
  return __builtin_amdgcn_mfma_f32_16x16x32_bf16(a, b, c, 0, 0, 0);
}
__device__ __forceinline__ void gld16(const float* g, float* l) {
  __builtin_amdgcn_global_load_lds(
      (const __attribute__((address_space(1))) unsigned int*)g,
      (__attribute__((address_space(3))) unsigned int*)l, 16, 0, 0);
}

// LDS: max(lstm: 4*16*74*4 + 64 + 2560 = 21568, lf8: 8*768*4 + 8*128*4
// = 28672)  -> 28736 bytes; 4 blocks/CU = 114.9KB < 160KB.
#define SMEM_BYTES 28736

template <int D, int NK32>
__device__ void lstm2w(const float* __restrict__ x,
                       const float* __restrict__ Wih,
                       const float* __restrict__ Whh,
                       const float* __restrict__ bih,
                       const float* __restrict__ bhh,
                       const float* __restrict__ Wo,
                       const float* __restrict__ bo,
                       float* __restrict__ outf, int n0, char* smem) {
  constexpr int FPS = 16 * D;    // floats per ring slot
  constexpr int UPS = FPS / 4;   // 16B units per slot
  constexpr int FULL = UPS / 64;
  constexpr int REM = UPS % 64;

  float* xbuf = (float*)smem;                                   // [4][FPS]
  unsigned short* Hu = (unsigned short*)(smem + 4 * FPS * 4 + 64);

  const int tid = threadIdx.x;
  const int wid = tid >> 6;   // 0..1
  const int lane = tid & 63;
  const int c = lane & 15;
  const int q = lane >> 4;

  auto stageslot = [&](int t) {
    const float* gs = x + (size_t)t * (N_SAMPLES * D) + (size_t)n0 * D;
    float* ls = xbuf + (t & 3) * FPS;
#pragma unroll
    for (int r = 0; r < FULL; ++r)
      gld16(gs + (r * 64 + lane) * 4, ls + r * 256);
    if (REM) {
      if (lane < REM) gld16(gs + (FULL * 64 + lane) * 4, ls + FULL * 256);
    }
  };

  // prologue staging: even slots by wave0, odd by wave1
  if (wid == 0) { stageslot(0); stageslot(2); }
  else          { stageslot(1); }

  // stationary weights: 4 tiles (16 units) per wave; weight zeros beyond D
  // carry the x tail masking implicitly.
  short8v wfx[4][NK32], wfh[4];
  float4v binit[4];
#pragma unroll
  for (int T = 0; T < 4; ++T) {
    const int G = (c & 3) * 32 + wid * 16 + (c >> 2) * 4 + T;  // A-row c
    const float* wr = Wih + G * D;
#pragma unroll
    for (int kt = 0; kt < NK32; ++kt) {
      short8v s;
#pragma unroll
      for (int e = 0; e < 8; ++e) {
        const int d = kt * 32 + q * 8 + e;
        s[e] = (d < D) ? bf16r(wr[d]) : (short)0;
      }
      wfx[T][kt] = s;
    }
    const float* hr = Whh + G * 32;
#pragma unroll
    for (int e = 0; e < 8; ++e) wfh[T][e] = bf16r(hr[q * 8 + e]);
#pragma unroll
    for (int r = 0; r < 4; ++r) {
      const int Gr = r * 32 + wid * 16 + q * 4 + T;  // C reg r mapping
      binit[T][r] = bih[Gr] + bhh[Gr];
    }
  }

  // zero both H buffers
  {
    unsigned* Hz = (unsigned*)Hu;
    for (int i = tid; i < 640; i += 128) Hz[i] = 0;
  }

  VM0;    // own prologue slots landed
  LGKM0;  // H zeros visible
  __builtin_amdgcn_s_barrier();

  auto ldcvt = [&](const float* xs0, short8v* xo) {
    const float* xs = xs0 + c * D;
#pragma unroll
    for (int kt = 0; kt < NK32; ++kt) {
      const float* p = xs + kt * 32 + q * 8;
      const float2v r0 = *(const float2v*)(p);
      const float2v r1 = *(const float2v*)(p + 2);
      const float2v r2 = *(const float2v*)(p + 4);
      const float2v r3 = *(const float2v*)(p + 6);
      union { short8v s; unsigned u[4]; } fr;
      fr.u[0] = cvt_pk_bf16(r0[0], r0[1]);
      fr.u[1] = cvt_pk_bf16(r1[0], r1[1]);
      fr.u[2] = cvt_pk_bf16(r2[0], r2[1]);
      fr.u[3] = cvt_pk_bf16(r3[0], r3[1]);
      xo[kt] = fr.s;
    }
  };

  float cst[4] = {0.0f, 0.0f, 0.0f, 0.0f};
  float4v gxA[4], gxB[4];
  {
    short8v xF[NK32];
    ldcvt(xbuf, xF);  // slot 0 = x[0]
#pragma unroll
    for (int T = 0; T < 4; ++T) {
      float4v g4 = binit[T];
#pragma unroll
      for (int kt = 0; kt < NK32; ++kt) g4 = mfma32(wfx[T][kt], xF[kt], g4);
      gxA[T] = g4;
    }
  }

  // one step; i = t&3 compile-time, gc = gates for t, gn -> gates for t+1.
  auto STEP = [&](int t, int i, float4v (&gc)[4], float4v (&gn)[4]) {
    const int pb = i & 1;
    // on-chain: h of step t-1 (all 32 units)
    const short8v hB = *(const short8v*)(Hu + pb * HBUF + c * HSTR + q * 8);
    // staging: slot (t+3)&3 by wave (i+3)&1
    if (((i + 3) & 1) == wid && t + 3 < T_STEPS) stageslot(t + 3);
    // off-chain: x[t+1] frags + production
    short8v xN[NK32];
    ldcvt(xbuf + ((i + 1) & 3) * FPS, xN);
#pragma unroll
    for (int T = 0; T < 4; ++T) {
      float4v g4 = binit[T];
#pragma unroll
      for (int kt = 0; kt < NK32; ++kt) g4 = mfma32(wfx[T][kt], xN[kt], g4);
      gn[T] = g4;
    }
    // on-chain: 4 h-MFMAs + lean trans (prioritized)
    __builtin_amdgcn_s_setprio(1);
    float hv[4];
#pragma unroll
    for (int T = 0; T < 4; ++T) {
      const float4v acc = mfma32(wfh[T], hB, gc[T]);
      const float iv = sigm_(acc[0]);
      const float fv = sigm_(acc[1]);
      const float gv = tanh_(acc[2]);
      const float ov = sigm_(acc[3]);
      const float cv = fv * cst[T] + iv * gv;
      cst[T] = cv;
      hv[T] = ov * tanh_(cv);
    }
    uint2v hp;
    hp[0] = cvt_pk_bf16(hv[0], hv[1]);
    hp[1] = cvt_pk_bf16(hv[2], hv[3]);
    *(uint2v*)(Hu + (1 - pb) * HBUF + c * HSTR + wid * 16 + q * 4) = hp;
    __builtin_amdgcn_s_setprio(0);
    LGKM0;  // h write (and ds reads) drained
    if ((i & 1) == wid) { VM0; }  // drain own slot t+2 stage (issued t-1)
    __builtin_amdgcn_s_barrier();
  };

  for (int tb = 0; tb < T_STEPS; tb += 8) {
    STEP(tb + 0, 0, gxA, gxB);
    STEP(tb + 1, 1, gxB, gxA);
    STEP(tb + 2, 2, gxA, gxB);
    STEP(tb + 3, 3, gxB, gxA);
    STEP(tb + 4, 0, gxA, gxB);
    STEP(tb + 5, 1, gxB, gxA);
    STEP(tb + 6, 2, gxA, gxB);
    STEP(tb + 7, 3, gxB, gxA);
  }

  // epilogue: h[255] in H buffer 0 (t=255 odd writes pb^1=0)
  {
    const short8v hB = *(const short8v*)(Hu + c * HSTR + q * 8);
    const float* wor = Wo + (16 * wid + c) * 32;
    short8v w8;
#pragma unroll
    for (int e = 0; e < 8; ++e) w8[e] = bf16r(wor[q * 8 + e]);
    float4v o4 = {0.0f, 0.0f, 0.0f, 0.0f};
    o4 = mfma32(w8, hB, o4);
    float4v res;
#pragma unroll
    for (int r = 0; r < 4; ++r)
      res[r] = fmaxf(o4[r] + bo[16 * wid + q * 4 + r], 0.0f);
    *(float4v*)(outf + (size_t)(n0 + c) * 32 + 16 * wid + q * 4) = res;
  }
}

// lf path: 8 samples per block, 128 threads.
__device__ void lf8(const float* __restrict__ l, const float* __restrict__ lW1,
                    const float* __restrict__ lb1,
                    const float* __restrict__ lW2,
                    const float* __restrict__ lb2, float* __restrict__ lf,
                    int n0, char* smem) {
  float* lsh = (float*)smem;          // 8*768 floats
  float* h1sh = lsh + 8 * 768;        // 8*128 floats
  const int tid = threadIdx.x;

  {
    const float4v* src = (const float4v*)(l + (size_t)n0 * 768);
    float4v* dst = (float4v*)lsh;
#pragma unroll
    for (int i = 0; i < 12; ++i) dst[tid + i * 128] = src[tid + i * 128];
  }
  __syncthreads();

  {  // phase 1: h1[8][128]; thread = one u of 128, all 8 samples
    const int u = tid;
    float acc[8];
#pragma unroll
    for (int i = 0; i < 8; ++i) acc[i] = 0.0f;
    const float4v* wrow = (const float4v*)(lW1 + u * 768);
    for (int k4 = 0; k4 < 192; ++k4) {
      const float4v w = wrow[k4];
#pragma unroll
      for (int i = 0; i < 8; ++i) {
        const float4v xv = ((const float4v*)(lsh + i * 768))[k4];
        acc[i] += w[0] * xv[0] + w[1] * xv[1] + w[2] * xv[2] + w[3] * xv[3];
      }
    }
    const float b = lb1[u];
#pragma unroll
    for (int i = 0; i < 8; ++i)
      h1sh[i * 128 + u] = fmaxf(acc[i] + b, 0.0f);
  }
  __syncthreads();

  {  // phase 2: lf[8][32]; thread -> (u2, samples sg and sg+4)
    const int u2 = tid & 31;
    const int sg = tid >> 5;  // 0..3
    float acc0 = 0.0f, acc1 = 0.0f;
    const float4v* w2 = (const float4v*)(lW2 + u2 * 128);
#pragma unroll
    for (int k4 = 0; k4 < 32; ++k4) {
      const float4v w = w2[k4];
      const float4v xa = ((const float4v*)(h1sh + sg * 128))[k4];
      const float4v xb = ((const float4v*)(h1sh + (sg + 4) * 128))[k4];
      acc0 += w[0] * xa[0] + w[1] * xa[1] + w[2] * xa[2] + w[3] * xa[3];
      acc1 += w[0] * xb[0] + w[1] * xb[1] + w[2] * xb[2] + w[3] * xb[3];
    }
    const float b2 = lb2[u2];
    lf[(size_t)(n0 + sg) * 32 + u2] = fmaxf(acc0 + b2, 0.0f);
    lf[(size_t)(n0 + sg + 4) * 32 + u2] = fmaxf(acc1 + b2, 0.0f);
  }
}

__global__ __launch_bounds__(128, 2) void front_kernel(
    const float* __restrict__ a, const float* __restrict__ v,
    const float* __restrict__ aWih, const float* __restrict__ aWhh,
    const float* __restrict__ abih, const float* __restrict__ abhh,
    const float* __restrict__ aWo, const float* __restrict__ abo,
    const float* __restrict__ vWih, const float* __restrict__ vWhh,
    const float* __restrict__ vbih, const float* __restrict__ vbhh,
    const float* __restrict__ vWo, const float* __restrict__ vbo,
    const float* __restrict__ l, const float* __restrict__ lW1,
    const float* __restrict__ lb1, const float* __restrict__ lW2,
    const float* __restrict__ lb2, float* __restrict__ lfw,
    float* __restrict__ afw, float* __restrict__ vfw) {
  __shared__ __align__(16) char smem[SMEM_BYTES];
  const int b = blockIdx.x;
  if (b < 512) {
    lf8(l, lW1, lb1, lW2, lb2, lfw, b * 8, smem);
  } else if (b < 768) {
    lstm2w<74, 3>(a, aWih, aWhh, abih, abhh, aWo, abo, afw, (b - 512) * 16,
                  smem);
  } else {
    lstm2w<47, 2>(v, vWih, vWhh, vbih, vbhh, vWo, vbo, vfw, (b - 768) * 16,
                  smem);
  }
}

// ---------------------------------------------------------------------------
// Transformer block + post-fusion head. 32 lanes/sample, 8 samples/block.
// ---------------------------------------------------------------------------
__global__ __launch_bounds__(256) void head_kernel(
    const float* __restrict__ lf, const float* __restrict__ af,
    const float* __restrict__ vf, const float* __restrict__ Wq,
    const float* __restrict__ bq, const float* __restrict__ Wk,
    const float* __restrict__ bk, const float* __restrict__ Wv,
    const float* __restrict__ bv, const float* __restrict__ Wz,
    const float* __restrict__ bz, const float* __restrict__ Wff,
    const float* __restrict__ bff, const float* __restrict__ g1,
    const float* __restrict__ be1, const float* __restrict__ g2,
    const float* __restrict__ be2, const float* __restrict__ Wp1,
    const float* __restrict__ bp1, const float* __restrict__ Wp2,
    const float* __restrict__ bp2, float* __restrict__ out) {
  __shared__ float shA[8][3][33];
  __shared__ float shB[8][3][33];
  const int tid = threadIdx.x;
  const int j = tid & 31;
  const int slot = tid >> 5;
  const int n = blockIdx.x * 8 + slot;
  const size_t off = (size_t)n * 32 + j;

  const float x0 = lf[off], x1 = af[off], x2 = vf[off];

  auto ln3 = [&](float a0, float a1, float a2, const float* g,
                 const float* be, float* o) {
    float s = a0 + a1 + a2;
    s += __shfl_xor(s, 1); s += __shfl_xor(s, 2); s += __shfl_xor(s, 4);
    s += __shfl_xor(s, 8); s += __shfl_xor(s, 16);
    const float mu = s * (1.0f / 96.0f);
    const float d0 = a0 - mu, d1 = a1 - mu, d2 = a2 - mu;
    float ss = d0 * d0 + d1 * d1 + d2 * d2;
    ss += __shfl_xor(ss, 1); ss += __shfl_xor(ss, 2); ss += __shfl_xor(ss, 4);
    ss += __shfl_xor(ss, 8); ss += __shfl_xor(ss, 16);
    const float rs = rsqrtf(ss * (1.0f / 96.0f) + 1e-5f);
    o[0] = d0 * rs * g[j] + be[j];
    o[1] = d1 * rs * g[32 + j] + be[32 + j];
    o[2] = d2 * rs * g[64 + j] + be[64 + j];
  };

  float z[3];
  ln3(x0, x1, x2, g1, be1, z);
  shA[slot][0][j] = z[0]; shA[slot][1][j] = z[1]; shA[slot][2][j] = z[2];
  __syncthreads();

  float qv[3], kv[3], vv[3];
  {
    const float bqj = bq[j], bkj = bk[j], bvj = bv[j];
    qv[0] = bqj; qv[1] = bqj; qv[2] = bqj;
    kv[0] = bkj; kv[1] = bkj; kv[2] = bkj;
    vv[0] = bvj; vv[1] = bvj; vv[2] = bvj;
    const float* wqr = Wq + j * 32;
    const float* wkr = Wk + j * 32;
    const float* wvr = Wv + j * 32;
#pragma unroll 8
    for (int k = 0; k < 32; ++k) {
      const float zz0 = shA[slot][0][k], zz1 = shA[slot][1][k],
                  zz2 = shA[slot][2][k];
      const float wq = wqr[k], wk_ = wkr[k], wv_ = wvr[k];
      qv[0] += wq * zz0;  qv[1] += wq * zz1;  qv[2] += wq * zz2;
      kv[0] += wk_ * zz0; kv[1] += wk_ * zz1; kv[2] += wk_ * zz2;
      vv[0] += wv_ * zz0; vv[1] += wv_ * zz1; vv[2] += wv_ * zz2;
    }
  }

  float at[3][3];
#pragma unroll
  for (int s = 0; s < 3; ++s)
#pragma unroll
    for (int t2 = 0; t2 < 3; ++t2) {
      float p = qv[s] * kv[t2];
      p += __shfl_xor(p, 1); p += __shfl_xor(p, 2); p += __shfl_xor(p, 4);
      at[s][t2] = p;
    }
#pragma unroll
  for (int s = 0; s < 3; ++s) {
    const float m = fmaxf(fmaxf(at[s][0], at[s][1]), at[s][2]);
    const float e0 = __expf(at[s][0] - m), e1 = __expf(at[s][1] - m),
                e2 = __expf(at[s][2] - m);
    const float sc = 0.35355339059327373f * __fdividef(1.0f, e0 + e1 + e2);
    at[s][0] = e0 * sc; at[s][1] = e1 * sc; at[s][2] = e2 * sc;
  }
  float zc[3];
#pragma unroll
  for (int s = 0; s < 3; ++s)
    zc[s] = at[s][0] * vv[0] + at[s][1] * vv[1] + at[s][2] * vv[2];
  shB[slot][0][j] = zc[0]; shB[slot][1][j] = zc[1]; shB[slot][2][j] = zc[2];
  __syncthreads();

  const float bzj = bz[j];
  float z2a[3] = {bzj + x0, bzj + x1, bzj + x2};
  {
    const float* wzr = Wz + j * 32;
#pragma unroll 8
    for (int k = 0; k < 32; ++k) {
      const float w = wzr[k];
      z2a[0] += w * shB[slot][0][k];
      z2a[1] += w * shB[slot][1][k];
      z2a[2] += w * shB[slot][2][k];
    }
  }

  float zn[3];
  ln3(z2a[0], z2a[1], z2a[2], g2, be2, zn);
  shA[slot][0][j] = zn[0]; shA[slot][1][j] = zn[1]; shA[slot][2][j] = zn[2];
  __syncthreads();

  const float bffj = bff[j];
  float Za[3] = {bffj + z2a[0], bffj + z2a[1], bffj + z2a[2]};
  {
    const float* wfr = Wff + j * 32;
#pragma unroll 8
    for (int k = 0; k < 32; ++k) {
      const float w = wfr[k];
      Za[0] += w * shA[slot][0][k];
      Za[1] += w * shA[slot][1][k];
      Za[2] += w * shA[slot][2][k];
    }
  }
  shB[slot][0][j] = Za[0]; shB[slot][1][j] = Za[1]; shB[slot][2][j] = Za[2];
  __syncthreads();

  float p = bp1[j];
  {
    const float* wpr = Wp1 + j * 96;
#pragma unroll
    for (int s = 0; s < 3; ++s)
#pragma unroll 8
      for (int k = 0; k < 32; ++k) p += wpr[s * 32 + k] * shB[slot][s][k];
  }
  p = fmaxf(p, 0.0f);
  float l0 = Wp2[j] * p, l1 = Wp2[32 + j] * p;
  l0 += __shfl_xor(l0, 1); l0 += __shfl_xor(l0, 2); l0 += __shfl_xor(l0, 4);
  l0 += __shfl_xor(l0, 8); l0 += __shfl_xor(l0, 16);
  l1 += __shfl_xor(l1, 1); l1 += __shfl_xor(l1, 2); l1 += __shfl_xor(l1, 4);
  l1 += __shfl_xor(l1, 8); l1 += __shfl_xor(l1, 16);
  l0 += bp2[0]; l1 += bp2[1];
  const float mx = fmaxf(l0, l1);
  const float e0 = __expf(l0 - mx), e1 = __expf(l1 - mx);
  const float inv = __fdividef(1.0f, e0 + e1);
  if (j == 0) {
    out[(size_t)n * 2 + 0] = e0 * inv;
    out[(size_t)n * 2 + 1] = e1 * inv;
  }
}

// ---------------------------------------------------------------------------
extern "C" void kernel_launch(void* const* d_in, const int* in_sizes, int n_in,
                              void* d_out, int out_size, void* d_ws,
                              size_t ws_size, hipStream_t stream) {
  const float* l    = (const float*)d_in[0];
  const float* a    = (const float*)d_in[1];
  const float* v    = (const float*)d_in[2];
  const float* lW1  = (const float*)d_in[3];
  const float* lb1  = (const float*)d_in[4];
  const float* lW2  = (const float*)d_in[5];
  const float* lb2  = (const float*)d_in[6];
  const float* aWih = (const float*)d_in[7];
  const float* aWhh = (const float*)d_in[8];
  const float* abih = (const float*)d_in[9];
  const float* abhh = (const float*)d_in[10];
  const float* aWo  = (const float*)d_in[11];
  const float* abo  = (const float*)d_in[12];
  const float* vWih = (const float*)d_in[13];
  const float* vWhh = (const float*)d_in[14];
  const float* vbih = (const float*)d_in[15];
  const float* vbhh = (const float*)d_in[16];
  const float* vWo  = (const float*)d_in[17];
  const float* vbo  = (const float*)d_in[18];
  const float* Wq   = (const float*)d_in[19];
  const float* bq   = (const float*)d_in[20];
  const float* Wk   = (const float*)d_in[21];
  const float* bk   = (const float*)d_in[22];
  const float* Wv   = (const float*)d_in[23];
  const float* bv   = (const float*)d_in[24];
  const float* Wz   = (const float*)d_in[25];
  const float* bz   = (const float*)d_in[26];
  const float* Wff  = (const float*)d_in[27];
  const float* bff  = (const float*)d_in[28];
  const float* g1   = (const float*)d_in[29];
  const float* be1  = (const float*)d_in[30];
  const float* g2   = (const float*)d_in[31];
  const float* be2  = (const float*)d_in[32];
  const float* Wp1  = (const float*)d_in[33];
  const float* bp1  = (const float*)d_in[34];
  const float* Wp2  = (const float*)d_in[35];
  const float* bp2  = (const float*)d_in[36];

  float* out = (float*)d_out;
  float* ws = (float*)d_ws;
  float* lfw = ws;
  float* afw = ws + 4096 * 32;
  float* vfw = ws + 2 * 4096 * 32;

  hipLaunchKernelGGL(front_kernel, dim3(1024), dim3(128), 0, stream, a, v,
                     aWih, aWhh, abih, abhh, aWo, abo, vWih, vWhh, vbih,
                     vbhh, vWo, vbo, l, lW1, lb1, lW2, lb2, lfw, afw, vfw);
  hipLaunchKernelGGL(head_kernel, dim3(512), dim3(256), 0, stream, lfw, afw,
                     vfw, Wq, bq, Wk, bk, Wv, bv, Wz, bz, Wff, bff, g1, be1,
                     g2, be2, Wp1, bp1, Wp2, bp2, out);
}

// Round 14
// 231.923 us; speedup vs baseline: 1.9614x; 1.1956x over previous
//
#include <hip/hip_runtime.h>

// ---------------------------------------------------------------------------
// Fused multimodal net: [lf-MLP + 2 LSTMs] in ONE launch + transformer head.
// N=4096, T=256, DA=74, DV=47, hidden=32.
//
// Front kernel grid = 1024 blocks x 128 threads, 28.7KB LDS => 4 blocks/CU,
// all co-resident: blocks 0-511 = lf-MLP (8 samples), 512-767 = a-LSTM,
// 768-1023 = v-LSTM.
//
// LSTM (r13 champion + x register-prefetch): 2 waves per 16-sample group.
// Row map: gate row G = r*32 + wid*16 + q*4 + T -> lane (q,c) C-regs 0..3 =
// i,f,g,o of unit wid*16+q*4+T; lane's 4 h values contiguous => 2 cvt_pk +
// 1 ds_write_b64; h via ping-pong LDS, 1 barrier/step.
// Pipeline per step t: h-read | stage slot t+3 (running-pointer addr, turn
// = wave (t+3)&1, vmcnt(0) drained SAME step) | convert reg-raw x[t+1] ->
// frags (no LDS latency on serial path) | production MFMAs -> gates t+1 |
// issue raw ds_reads of x[t+2] into regs (latency hides under trans) |
// h-MFMA + lean trans + h-write | lgkm0 + (stager vm0) + barrier.
// ---------------------------------------------------------------------------

typedef float float4v __attribute__((ext_vector_type(4)));
typedef float float2v __attribute__((ext_vector_type(2)));
typedef short short8v __attribute__((ext_vector_type(8)));
typedef unsigned uint2v __attribute__((ext_vector_type(2)));

#define N_SAMPLES 4096
#define T_STEPS 256
#define HSTR 40           // shorts per sample row in H (32 units + pad)
#define HBUF (16 * HSTR)  // shorts per H buffer

#define LGKM0 asm volatile("s_waitcnt lgkmcnt(0)" ::: "memory")
#define VM0 asm volatile("s_waitcnt vmcnt(0)" ::: "memory")

__device__ __forceinline__ short bf16r(float f) {
  unsigned u = __float_as_uint(f);
  u += 0x7FFFu + ((u >> 16) & 1u);
  return (short)(u >> 16);
}
__device__ __forceinline__ unsigned cvt_pk_bf16(float lo, float hi) {
  unsigned r;
  asm("v_cvt_pk_bf16_f32 %0, %1, %2" : "=v"(r) : "v"(lo), "v"(hi));
  return r;
}
__device__ __forceinline__ float sigm_(float x) {
  return __builtin_amdgcn_rcpf(1.0f +
                               __builtin_amdgcn_exp2f(x * -1.44269504f));
}
__device__ __forceinline__ float tanh_(float x) {
  return 1.0f - 2.0f * __builtin_amdgcn_rcpf(
                           1.0f + __builtin_amdgcn_exp2f(x * 2.88539009f));
}
__device__ __forceinline__ float4v mfma32(short8v a, short8v b, float4v c) {
  return __builtin_amdgcn_mfma_f32_16x16x32_bf16(a, b, c, 0, 0, 0);
}
__device__ __forceinline__ void gld16(const float* g, float* l) {
  __builtin_amdgcn_global_load_lds(
      (const __attribute__((address_space(1))) unsigned int*)g,
      (__attribute__((address_space(3))) unsigned int*)l, 16, 0, 0);
}

// LDS: max(lstm: 4*16*74*4 + 64 + 2560 = 21568, lf8: 28672) -> 28736
#define SMEM_BYTES 28736

template <int D, int NK32>
__device__ void lstm2w(const float* __restrict__ x,
                       const float* __restrict__ Wih,
                       const float* __restrict__ Whh,
                       const float* __restrict__ bih,
                       const float* __restrict__ bhh,
                       const float* __restrict__ Wo,
                       const float* __restrict__ bo,
                       float* __restrict__ outf, int n0, char* smem) {
  constexpr int FPS = 16 * D;    // floats per ring slot
  constexpr int UPS = FPS / 4;   // 16B units per slot
  constexpr int FULL = UPS / 64;
  constexpr int REM = UPS % 64;

  float* xbuf = (float*)smem;                                   // [4][FPS]
  unsigned short* Hu = (unsigned short*)(smem + 4 * FPS * 4 + 64);

  const int tid = threadIdx.x;
  const int wid = tid >> 6;   // 0..1
  const int lane = tid & 63;
  const int c = lane & 15;
  const int q = lane >> 4;

  // running global pointer per wave: advances by 2 steps' worth per stage.
  const float* gsrun = x + (size_t)wid * (N_SAMPLES * D) + (size_t)n0 * D;

  auto stageslot = [&](float* ls) {
#pragma unroll
    for (int r = 0; r < FULL; ++r)
      gld16(gsrun + (r * 64 + lane) * 4, ls + r * 256);
    if (REM) {
      if (lane < REM) gld16(gsrun + (FULL * 64 + lane) * 4, ls + FULL * 256);
    }
    gsrun += 2 * (N_SAMPLES * D);
  };

  // prologue staging: wave0 -> slots 0,2 ; wave1 -> slot 1
  if (wid == 0) { stageslot(xbuf); stageslot(xbuf + 2 * FPS); }
  else          { stageslot(xbuf + 1 * FPS); }

  // stationary weights: 4 tiles (16 units) per wave; weight zeros beyond D
  // carry the x tail masking implicitly.
  short8v wfx[4][NK32], wfh[4];
  float4v binit[4];
#pragma unroll
  for (int T = 0; T < 4; ++T) {
    const int G = (c & 3) * 32 + wid * 16 + (c >> 2) * 4 + T;  // A-row c
    const float* wr = Wih + G * D;
#pragma unroll
    for (int kt = 0; kt < NK32; ++kt) {
      short8v s;
#pragma unroll
      for (int e = 0; e < 8; ++e) {
        const int d = kt * 32 + q * 8 + e;
        s[e] = (d < D) ? bf16r(wr[d]) : (short)0;
      }
      wfx[T][kt] = s;
    }
    const float* hr = Whh + G * 32;
#pragma unroll
    for (int e = 0; e < 8; ++e) wfh[T][e] = bf16r(hr[q * 8 + e]);
#pragma unroll
    for (int r = 0; r < 4; ++r) {
      const int Gr = r * 32 + wid * 16 + q * 4 + T;  // C reg r mapping
      binit[T][r] = bih[Gr] + bhh[Gr];
    }
  }

  // zero both H buffers
  {
    unsigned* Hz = (unsigned*)Hu;
    for (int i = tid; i < 640; i += 128) Hz[i] = 0;
  }

  VM0;    // own prologue slots landed
  LGKM0;  // H zeros visible
  __builtin_amdgcn_s_barrier();

  float cst[4] = {0.0f, 0.0f, 0.0f, 0.0f};
  float4v gxA[4], gxB[4];
  float2v nxr[NK32][4];  // raw x[t+1] prefetched into registers

  {
    // gates for t=0 from slot 0 (one-time direct LDS read+cvt)
    const float* xs = xbuf + c * D;
    short8v xF[NK32];
#pragma unroll
    for (int kt = 0; kt < NK32; ++kt) {
      const float* p = xs + kt * 32 + q * 8;
      const float2v r0 = *(const float2v*)(p);
      const float2v r1 = *(const float2v*)(p + 2);
      const float2v r2 = *(const float2v*)(p + 4);
      const float2v r3 = *(const float2v*)(p + 6);
      union { short8v s; unsigned u[4]; } fr;
      fr.u[0] = cvt_pk_bf16(r0[0], r0[1]);
      fr.u[1] = cvt_pk_bf16(r1[0], r1[1]);
      fr.u[2] = cvt_pk_bf16(r2[0], r2[1]);
      fr.u[3] = cvt_pk_bf16(r3[0], r3[1]);
      xF[kt] = fr.s;
    }
#pragma unroll
    for (int T = 0; T < 4; ++T) {
      float4v g4 = binit[T];
#pragma unroll
      for (int kt = 0; kt < NK32; ++kt) g4 = mfma32(wfx[T][kt], xF[kt], g4);
      gxA[T] = g4;
    }
    // raw x[1] from slot 1
    const float* xs1 = xbuf + FPS + c * D;
#pragma unroll
    for (int kt = 0; kt < NK32; ++kt) {
      const float* p = xs1 + kt * 32 + q * 8;
      nxr[kt][0] = *(const float2v*)(p);
      nxr[kt][1] = *(const float2v*)(p + 2);
      nxr[kt][2] = *(const float2v*)(p + 4);
      nxr[kt][3] = *(const float2v*)(p + 6);
    }
  }

  // one step; i = t&3 compile-time. Entry state: gc = gates(t), nxr = raw
  // x[t+1]. Produces gn = gates(t+1), nxr = raw x[t+2].
  auto STEP = [&](int t, int i, float4v (&gc)[4], float4v (&gn)[4]) {
    const int pb = i & 1;
    const bool mystage = (((i + 3) & 1) == wid);
    // on-chain: h of step t-1 (all 32 units)
    const short8v hB = *(const short8v*)(Hu + pb * HBUF + c * HSTR + q * 8);
    // staging: slot (t+3)&3 by wave (i+3)&1 (running pointer)
    if (mystage && t + 3 < T_STEPS) stageslot(xbuf + ((i + 3) & 3) * FPS);
    // convert prefetched raw x[t+1] -> frags (no LDS latency here)
    short8v xN[NK32];
#pragma unroll
    for (int kt = 0; kt < NK32; ++kt) {
      union { short8v s; unsigned u[4]; } fr;
      fr.u[0] = cvt_pk_bf16(nxr[kt][0][0], nxr[kt][0][1]);
      fr.u[1] = cvt_pk_bf16(nxr[kt][1][0], nxr[kt][1][1]);
      fr.u[2] = cvt_pk_bf16(nxr[kt][2][0], nxr[kt][2][1]);
      fr.u[3] = cvt_pk_bf16(nxr[kt][3][0], nxr[kt][3][1]);
      xN[kt] = fr.s;
    }
    // production MFMAs -> gates(t+1)
#pragma unroll
    for (int T = 0; T < 4; ++T) {
      float4v g4 = binit[T];
#pragma unroll
      for (int kt = 0; kt < NK32; ++kt) g4 = mfma32(wfx[T][kt], xN[kt], g4);
      gn[T] = g4;
    }
    // issue raw reads of x[t+2] (slot staged at t-1, drained end of t-1);
    // latency hides under the h-MFMA + trans chain below.
    {
      const float* xs2 = xbuf + ((i + 2) & 3) * FPS + c * D;
#pragma unroll
      for (int kt = 0; kt < NK32; ++kt) {
        const float* p = xs2 + kt * 32 + q * 8;
        nxr[kt][0] = *(const float2v*)(p);
        nxr[kt][1] = *(const float2v*)(p + 2);
        nxr[kt][2] = *(const float2v*)(p + 4);
        nxr[kt][3] = *(const float2v*)(p + 6);
      }
    }
    // on-chain: 4 h-MFMAs + lean trans (prioritized)
    __builtin_amdgcn_s_setprio(1);
    float hv[4];
#pragma unroll
    for (int T = 0; T < 4; ++T) {
      const float4v acc = mfma32(wfh[T], hB, gc[T]);
      const float iv = sigm_(acc[0]);
      const float fv = sigm_(acc[1]);
      const float gv = tanh_(acc[2]);
      const float ov = sigm_(acc[3]);
      const float cv = fv * cst[T] + iv * gv;
      cst[T] = cv;
      hv[T] = ov * tanh_(cv);
    }
    uint2v hp;
    hp[0] = cvt_pk_bf16(hv[0], hv[1]);
    hp[1] = cvt_pk_bf16(hv[2], hv[3]);
    *(uint2v*)(Hu + (1 - pb) * HBUF + c * HSTR + wid * 16 + q * 4) = hp;
    __builtin_amdgcn_s_setprio(0);
    LGKM0;                    // h write + nxr reads drained
    if (mystage) { VM0; }     // drain own stage issued this step
    __builtin_amdgcn_s_barrier();
  };

  for (int tb = 0; tb < T_STEPS; tb += 8) {
    STEP(tb + 0, 0, gxA, gxB);
    STEP(tb + 1, 1, gxB, gxA);
    STEP(tb + 2, 2, gxA, gxB);
    STEP(tb + 3, 3, gxB, gxA);
    STEP(tb + 4, 0, gxA, gxB);
    STEP(tb + 5, 1, gxB, gxA);
    STEP(tb + 6, 2, gxA, gxB);
    STEP(tb + 7, 3, gxB, gxA);
  }

  // epilogue: h[255] in H buffer 0 (t=255 odd writes pb^1=0)
  {
    const short8v hB = *(const short8v*)(Hu + c * HSTR + q * 8);
    const float* wor = Wo + (16 * wid + c) * 32;
    short8v w8;
#pragma unroll
    for (int e = 0; e < 8; ++e) w8[e] = bf16r(wor[q * 8 + e]);
    float4v o4 = {0.0f, 0.0f, 0.0f, 0.0f};
    o4 = mfma32(w8, hB, o4);
    float4v res;
#pragma unroll
    for (int r = 0; r < 4; ++r)
      res[r] = fmaxf(o4[r] + bo[16 * wid + q * 4 + r], 0.0f);
    *(float4v*)(outf + (size_t)(n0 + c) * 32 + 16 * wid + q * 4) = res;
  }
}

// lf path: 8 samples per block, 128 threads.
__device__ void lf8(const float* __restrict__ l, const float* __restrict__ lW1,
                    const float* __restrict__ lb1,
                    const float* __restrict__ lW2,
                    const float* __restrict__ lb2, float* __restrict__ lf,
                    int n0, char* smem) {
  float* lsh = (float*)smem;          // 8*768 floats
  float* h1sh = lsh + 8 * 768;        // 8*128 floats
  const int tid = threadIdx.x;

  {
    const float4v* src = (const float4v*)(l + (size_t)n0 * 768);
    float4v* dst = (float4v*)lsh;
#pragma unroll
    for (int i = 0; i < 12; ++i) dst[tid + i * 128] = src[tid + i * 128];
  }
  __syncthreads();

  {  // phase 1: h1[8][128]; thread = one u of 128, all 8 samples
    const int u = tid;
    float acc[8];
#pragma unroll
    for (int i = 0; i < 8; ++i) acc[i] = 0.0f;
    const float4v* wrow = (const float4v*)(lW1 + u * 768);
    for (int k4 = 0; k4 < 192; ++k4) {
      const float4v w = wrow[k4];
#pragma unroll
      for (int i = 0; i < 8; ++i) {
        const float4v xv = ((const float4v*)(lsh + i * 768))[k4];
        acc[i] += w[0] * xv[0] + w[1] * xv[1] + w[2] * xv[2] + w[3] * xv[3];
      }
    }
    const float b = lb1[u];
#pragma unroll
    for (int i = 0; i < 8; ++i)
      h1sh[i * 128 + u] = fmaxf(acc[i] + b, 0.0f);
  }
  __syncthreads();

  {  // phase 2: lf[8][32]
    const int u2 = tid & 31;
    const int sg = tid >> 5;  // 0..3
    float acc0 = 0.0f, acc1 = 0.0f;
    const float4v* w2 = (const float4v*)(lW2 + u2 * 128);
#pragma unroll
    for (int k4 = 0; k4 < 32; ++k4) {
      const float4v w = w2[k4];
      const float4v xa = ((const float4v*)(h1sh + sg * 128))[k4];
      const float4v xb = ((const float4v*)(h1sh + (sg + 4) * 128))[k4];
      acc0 += w[0] * xa[0] + w[1] * xa[1] + w[2] * xa[2] + w[3] * xa[3];
      acc1 += w[0] * xb[0] + w[1] * xb[1] + w[2] * xb[2] + w[3] * xb[3];
    }
    const float b2 = lb2[u2];
    lf[(size_t)(n0 + sg) * 32 + u2] = fmaxf(acc0 + b2, 0.0f);
    lf[(size_t)(n0 + sg + 4) * 32 + u2] = fmaxf(acc1 + b2, 0.0f);
  }
}

__global__ __launch_bounds__(128, 2) void front_kernel(
    const float* __restrict__ a, const float* __restrict__ v,
    const float* __restrict__ aWih, const float* __restrict__ aWhh,
    const float* __restrict__ abih, const float* __restrict__ abhh,
    const float* __restrict__ aWo, const float* __restrict__ abo,
    const float* __restrict__ vWih, const float* __restrict__ vWhh,
    const float* __restrict__ vbih, const float* __restrict__ vbhh,
    const float* __restrict__ vWo, const float* __restrict__ vbo,
    const float* __restrict__ l, const float* __restrict__ lW1,
    const float* __restrict__ lb1, const float* __restrict__ lW2,
    const float* __restrict__ lb2, float* __restrict__ lfw,
    float* __restrict__ afw, float* __restrict__ vfw) {
  __shared__ __align__(16) char smem[SMEM_BYTES];
  const int b = blockIdx.x;
  if (b < 512) {
    lf8(l, lW1, lb1, lW2, lb2, lfw, b * 8, smem);
  } else if (b < 768) {
    lstm2w<74, 3>(a, aWih, aWhh, abih, abhh, aWo, abo, afw, (b - 512) * 16,
                  smem);
  } else {
    lstm2w<47, 2>(v, vWih, vWhh, vbih, vbhh, vWo, vbo, vfw, (b - 768) * 16,
                  smem);
  }
}

// ---------------------------------------------------------------------------
// Transformer block + post-fusion head. 32 lanes/sample, 8 samples/block.
// ---------------------------------------------------------------------------
__global__ __launch_bounds__(256) void head_kernel(
    const float* __restrict__ lf, const float* __restrict__ af,
    const float* __restrict__ vf, const float* __restrict__ Wq,
    const float* __restrict__ bq, const float* __restrict__ Wk,
    const float* __restrict__ bk, const float* __restrict__ Wv,
    const float* __restrict__ bv, const float* __restrict__ Wz,
    const float* __restrict__ bz, const float* __restrict__ Wff,
    const float* __restrict__ bff, const float* __restrict__ g1,
    const float* __restrict__ be1, const float* __restrict__ g2,
    const float* __restrict__ be2, const float* __restrict__ Wp1,
    const float* __restrict__ bp1, const float* __restrict__ Wp2,
    const float* __restrict__ bp2, float* __restrict__ out) {
  __shared__ float shA[8][3][33];
  __shared__ float shB[8][3][33];
  const int tid = threadIdx.x;
  const int j = tid & 31;
  const int slot = tid >> 5;
  const int n = blockIdx.x * 8 + slot;
  const size_t off = (size_t)n * 32 + j;

  const float x0 = lf[off], x1 = af[off], x2 = vf[off];

  auto ln3 = [&](float a0, float a1, float a2, const float* g,
                 const float* be, float* o) {
    float s = a0 + a1 + a2;
    s += __shfl_xor(s, 1); s += __shfl_xor(s, 2); s += __shfl_xor(s, 4);
    s += __shfl_xor(s, 8); s += __shfl_xor(s, 16);
    const float mu = s * (1.0f / 96.0f);
    const float d0 = a0 - mu, d1 = a1 - mu, d2 = a2 - mu;
    float ss = d0 * d0 + d1 * d1 + d2 * d2;
    ss += __shfl_xor(ss, 1); ss += __shfl_xor(ss, 2); ss += __shfl_xor(ss, 4);
    ss += __shfl_xor(ss, 8); ss += __shfl_xor(ss, 16);
    const float rs = rsqrtf(ss * (1.0f / 96.0f) + 1e-5f);
    o[0] = d0 * rs * g[j] + be[j];
    o[1] = d1 * rs * g[32 + j] + be[32 + j];
    o[2] = d2 * rs * g[64 + j] + be[64 + j];
  };

  float z[3];
  ln3(x0, x1, x2, g1, be1, z);
  shA[slot][0][j] = z[0]; shA[slot][1][j] = z[1]; shA[slot][2][j] = z[2];
  __syncthreads();

  float qv[3], kv[3], vv[3];
  {
    const float bqj = bq[j], bkj = bk[j], bvj = bv[j];
    qv[0] = bqj; qv[1] = bqj; qv[2] = bqj;
    kv[0] = bkj; kv[1] = bkj; kv[2] = bkj;
    vv[0] = bvj; vv[1] = bvj; vv[2] = bvj;
    const float* wqr = Wq + j * 32;
    const float* wkr = Wk + j * 32;
    const float* wvr = Wv + j * 32;
#pragma unroll 8
    for (int k = 0; k < 32; ++k) {
      const float zz0 = shA[slot][0][k], zz1 = shA[slot][1][k],
                  zz2 = shA[slot][2][k];
      const float wq = wqr[k], wk_ = wkr[k], wv_ = wvr[k];
      qv[0] += wq * zz0;  qv[1] += wq * zz1;  qv[2] += wq * zz2;
      kv[0] += wk_ * zz0; kv[1] += wk_ * zz1; kv[2] += wk_ * zz2;
      vv[0] += wv_ * zz0; vv[1] += wv_ * zz1; vv[2] += wv_ * zz2;
    }
  }

  float at[3][3];
#pragma unroll
  for (int s = 0; s < 3; ++s)
#pragma unroll
    for (int t2 = 0; t2 < 3; ++t2) {
      float p = qv[s] * kv[t2];
      p += __shfl_xor(p, 1); p += __shfl_xor(p, 2); p += __shfl_xor(p, 4);
      at[s][t2] = p;
    }
#pragma unroll
  for (int s = 0; s < 3; ++s) {
    const float m = fmaxf(fmaxf(at[s][0], at[s][1]), at[s][2]);
    const float e0 = __expf(at[s][0] - m), e1 = __expf(at[s][1] - m),
                e2 = __expf(at[s][2] - m);
    const float sc = 0.35355339059327373f * __fdividef(1.0f, e0 + e1 + e2);
    at[s][0] = e0 * sc; at[s][1] = e1 * sc; at[s][2] = e2 * sc;
  }
  float zc[3];
#pragma unroll
  for (int s = 0; s < 3; ++s)
    zc[s] = at[s][0] * vv[0] + at[s][1] * vv[1] + at[s][2] * vv[2];
  shB[slot][0][j] = zc[0]; shB[slot][1][j] = zc[1]; shB[slot][2][j] = zc[2];
  __syncthreads();

  const float bzj = bz[j];
  float z2a[3] = {bzj + x0, bzj + x1, bzj + x2};
  {
    const float* wzr = Wz + j * 32;
#pragma unroll 8
    for (int k = 0; k < 32; ++k) {
      const float w = wzr[k];
      z2a[0] += w * shB[slot][0][k];
      z2a[1] += w * shB[slot][1][k];
      z2a[2] += w * shB[slot][2][k];
    }
  }

  float zn[3];
  ln3(z2a[0], z2a[1], z2a[2], g2, be2, zn);
  shA[slot][0][j] = zn[0]; shA[slot][1][j] = zn[1]; shA[slot][2][j] = zn[2];
  __syncthreads();

  const float bffj = bff[j];
  float Za[3] = {bffj + z2a[0], bffj + z2a[1], bffj + z2a[2]};
  {
    const float* wfr = Wff + j * 32;
#pragma unroll 8
    for (int k = 0; k < 32; ++k) {
      const float w = wfr[k];
      Za[0] += w * shA[slot][0][k];
      Za[1] += w * shA[slot][1][k];
      Za[2] += w * shA[slot][2][k];
    }
  }
  shB[slot][0][j] = Za[0]; shB[slot][1][j] = Za[1]; shB[slot][2][j] = Za[2];
  __syncthreads();

  float p = bp1[j];
  {
    const float* wpr = Wp1 + j * 96;
#pragma unroll
    for (int s = 0; s < 3; ++s)
#pragma unroll 8
      for (int k = 0; k < 32; ++k) p += wpr[s * 32 + k] * shB[slot][s][k];
  }
  p = fmaxf(p, 0.0f);
  float l0 = Wp2[j] * p, l1 = Wp2[32 + j] * p;
  l0 += __shfl_xor(l0, 1); l0 += __shfl_xor(l0, 2); l0 += __shfl_xor(l0, 4);
  l0 += __shfl_xor(l0, 8); l0 += __shfl_xor(l0, 16);
  l1 += __shfl_xor(l1, 1); l1 += __shfl_xor(l1, 2); l1 += __shfl_xor(l1, 4);
  l1 += __shfl_xor(l1, 8); l1 += __shfl_xor(l1, 16);
  l0 += bp2[0]; l1 += bp2[1];
  const float mx = fmaxf(l0, l1);
  const float e0 = __expf(l0 - mx), e1 = __expf(l1 - mx);
  const float inv = __fdividef(1.0f, e0 + e1);
  if (j == 0) {
    out[(size_t)n * 2 + 0] = e0 * inv;
    out[(size_t)n * 2 + 1] = e1 * inv;
  }
}

// ---------------------------------------------------------------------------
extern "C" void kernel_launch(void* const* d_in, const int* in_sizes, int n_in,
                              void* d_out, int out_size, void* d_ws,
                              size_t ws_size, hipStream_t stream) {
  const float* l    = (const float*)d_in[0];
  const float* a    = (const float*)d_in[1];
  const float* v    = (const float*)d_in[2];
  const float* lW1  = (const float*)d_in[3];
  const float* lb1  = (const float*)d_in[4];
  const float* lW2  = (const float*)d_in[5];
  const float* lb2  = (const float*)d_in[6];
  const float* aWih = (const float*)d_in[7];
  const float* aWhh = (const float*)d_in[8];
  const float* abih = (const float*)d_in[9];
  const float* abhh = (const float*)d_in[10];
  const float* aWo  = (const float*)d_in[11];
  const float* abo  = (const float*)d_in[12];
  const float* vWih = (const float*)d_in[13];
  const float* vWhh = (const float*)d_in[14];
  const float* vbih = (const float*)d_in[15];
  const float* vbhh = (const float*)d_in[16];
  const float* vWo  = (const float*)d_in[17];
  const float* vbo  = (const float*)d_in[18];
  const float* Wq   = (const float*)d_in[19];
  const float* bq   = (const float*)d_in[20];
  const float* Wk   = (const float*)d_in[21];
  const float* bk   = (const float*)d_in[22];
  const float* Wv   = (const float*)d_in[23];
  const float* bv   = (const float*)d_in[24];
  const float* Wz   = (const float*)d_in[25];
  const float* bz   = (const float*)d_in[26];
  const float* Wff  = (const float*)d_in[27];
  const float* bff  = (const float*)d_in[28];
  const float* g1   = (const float*)d_in[29];
  const float* be1  = (const float*)d_in[30];
  const float* g2   = (const float*)d_in[31];
  const float* be2  = (const float*)d_in[32];
  const float* Wp1  = (const float*)d_in[33];
  const float* bp1  = (const float*)d_in[34];
  const float* Wp2  = (const float*)d_in[35];
  const float* bp2  = (const float*)d_in[36];

  float* out = (float*)d_out;
  float* ws = (float*)d_ws;
  float* lfw = ws;
  float* afw = ws + 4096 * 32;
  float* vfw = ws + 2 * 4096 * 32;

  hipLaunchKernelGGL(front_kernel, dim3(1024), dim3(128), 0, stream, a, v,
                     aWih, aWhh, abih, abhh, aWo, abo, vWih, vWhh, vbih,
                     vbhh, vWo, vbo, l, lW1, lb1, lW2, lb2, lfw, afw, vfw);
  hipLaunchKernelGGL(head_kernel, dim3(512), dim3(256), 0, stream, lfw, afw,
                     vfw, Wq, bq, Wk, bk, Wv, bv, Wz, bz, Wff, bff, g1, be1,
                     g2, be2, Wp1, bp1, Wp2, bp2, out);
}

// Round 15
// 228.045 us; speedup vs baseline: 1.9948x; 1.0170x over previous
//
#include <hip/hip_runtime.h>

// ---------------------------------------------------------------------------
// Fused multimodal net: [lf-MLP + 2 LSTMs] in ONE launch + transformer head.
// N=4096, T=256, DA=74, DV=47, hidden=32.
//
// Front kernel grid = 1024 blocks x 128 threads, 28.7KB LDS => 4 blocks/CU,
// all co-resident: blocks 0-511 = lf-MLP (8 samples), 512-767 = a-LSTM,
// 768-1023 = v-LSTM.
//
// LSTM (r14 + distance-4 staging / next-step drain): 2 waves per 16-sample
// group. Row map: gate row G = r*32 + wid*16 + q*4 + T -> lane (q,c) C-regs
// 0..3 = i,f,g,o of unit wid*16+q*4+T; lane's 4 h values contiguous =>
// 2 cvt_pk + 1 ds_write_b64; h via ping-pong LDS, 1 barrier/step.
// Pipeline per step t: h-read | wave t&1 stages x[t+4] into slot t&3 (that
// slot's x[t] died at step t-2) | issue raw ds_reads of x[t+2] (slot staged
// t-2, drained/published end of t-1 => ~2 steps of HBM latency cover) |
// convert reg-raw x[t+1] -> frags | production MFMAs -> gates t+1 | h-MFMA +
// lean trans + h-write | lgkm0 | wave (t&1)^1 drains its step t-1 stage
// (vmcnt(0), exactly 1 outstanding) | barrier.
// ---------------------------------------------------------------------------

typedef float float4v __attribute__((ext_vector_type(4)));
typedef float float2v __attribute__((ext_vector_type(2)));
typedef short short8v __attribute__((ext_vector_type(8)));
typedef unsigned uint2v __attribute__((ext_vector_type(2)));

#define N_SAMPLES 4096
#define T_STEPS 256
#define HSTR 40           // shorts per sample row in H (32 units + pad)
#define HBUF (16 * HSTR)  // shorts per H buffer

#define LGKM0 asm volatile("s_waitcnt lgkmcnt(0)" ::: "memory")
#define VM0 asm volatile("s_waitcnt vmcnt(0)" ::: "memory")

__device__ __forceinline__ short bf16r(float f) {
  unsigned u = __float_as_uint(f);
  u += 0x7FFFu + ((u >> 16) & 1u);
  return (short)(u >> 16);
}
__device__ __forceinline__ unsigned cvt_pk_bf16(float lo, float hi) {
  unsigned r;
  asm("v_cvt_pk_bf16_f32 %0, %1, %2" : "=v"(r) : "v"(lo), "v"(hi));
  return r;
}
__device__ __forceinline__ float sigm_(float x) {
  return __builtin_amdgcn_rcpf(1.0f +
                               __builtin_amdgcn_exp2f(x * -1.44269504f));
}
__device__ __forceinline__ float tanh_(float x) {
  return 1.0f - 2.0f * __builtin_amdgcn_rcpf(
                           1.0f + __builtin_amdgcn_exp2f(x * 2.88539009f));
}
__device__ __forceinline__ float4v mfma32(short8v a, short8v b, float4v c) {
  return __builtin_amdgcn_mfma_f32_16x16x32_bf16(a, b, c, 0, 0, 0);
}
__device__ __forceinline__ void gld16(const float* g, float* l) {
  __builtin_amdgcn_global_load_lds(
      (const __attribute__((address_space(1))) unsigned int*)g,
      (__attribute__((address_space(3))) unsigned int*)l, 16, 0, 0);
}

// LDS: max(lstm: 4*16*74*4 + 64 + 2560 = 21568, lf8: 28672) -> 28736
#define SMEM_BYTES 28736

template <int D, int NK32>
__device__ void lstm2w(const float* __restrict__ x,
                       const float* __restrict__ Wih,
                       const float* __restrict__ Whh,
                       const float* __restrict__ bih,
                       const float* __restrict__ bhh,
                       const float* __restrict__ Wo,
                       const float* __restrict__ bo,
                       float* __restrict__ outf, int n0, char* smem) {
  constexpr int FPS = 16 * D;    // floats per ring slot
  constexpr int UPS = FPS / 4;   // 16B units per slot
  constexpr int FULL = UPS / 64;
  constexpr int REM = UPS % 64;

  float* xbuf = (float*)smem;                                   // [4][FPS]
  unsigned short* Hu = (unsigned short*)(smem + 4 * FPS * 4 + 64);

  const int tid = threadIdx.x;
  const int wid = tid >> 6;   // 0..1
  const int lane = tid & 63;
  const int c = lane & 15;
  const int q = lane >> 4;

  // running global pointer per wave: this wave stages x[wid], x[wid+2], ...
  const float* gsrun = x + (size_t)wid * (N_SAMPLES * D) + (size_t)n0 * D;

  auto stageslot = [&](float* ls) {
#pragma unroll
    for (int r = 0; r < FULL; ++r)
      gld16(gsrun + (r * 64 + lane) * 4, ls + r * 256);
    if (REM) {
      if (lane < REM) gld16(gsrun + (FULL * 64 + lane) * 4, ls + FULL * 256);
    }
    gsrun += 2 * (N_SAMPLES * D);
  };

  // prologue staging: x[0..3] -> wave0 slots 0,2 ; wave1 slots 1,3
  if (wid == 0) { stageslot(xbuf); stageslot(xbuf + 2 * FPS); }
  else          { stageslot(xbuf + 1 * FPS); stageslot(xbuf + 3 * FPS); }

  // stationary weights: 4 tiles (16 units) per wave; weight zeros beyond D
  // carry the x tail masking implicitly.
  short8v wfx[4][NK32], wfh[4];
  float4v binit[4];
#pragma unroll
  for (int T = 0; T < 4; ++T) {
    const int G = (c & 3) * 32 + wid * 16 + (c >> 2) * 4 + T;  // A-row c
    const float* wr = Wih + G * D;
#pragma unroll
    for (int kt = 0; kt < NK32; ++kt) {
      short8v s;
#pragma unroll
      for (int e = 0; e < 8; ++e) {
        const int d = kt * 32 + q * 8 + e;
        s[e] = (d < D) ? bf16r(wr[d]) : (short)0;
      }
      wfx[T][kt] = s;
    }
    const float* hr = Whh + G * 32;
#pragma unroll
    for (int e = 0; e < 8; ++e) wfh[T][e] = bf16r(hr[q * 8 + e]);
#pragma unroll
    for (int r = 0; r < 4; ++r) {
      const int Gr = r * 32 + wid * 16 + q * 4 + T;  // C reg r mapping
      binit[T][r] = bih[Gr] + bhh[Gr];
    }
  }

  // zero both H buffers
  {
    unsigned* Hz = (unsigned*)Hu;
    for (int i = tid; i < 640; i += 128) Hz[i] = 0;
  }

  VM0;    // own prologue slots landed
  LGKM0;  // H zeros visible
  __builtin_amdgcn_s_barrier();

  float cst[4] = {0.0f, 0.0f, 0.0f, 0.0f};
  float4v gxA[4], gxB[4];
  float2v nxr[NK32][4];  // raw x[t+1] prefetched into registers

  {
    // gates for t=0 from slot 0 (one-time direct LDS read+cvt)
    const float* xs = xbuf + c * D;
    short8v xF[NK32];
#pragma unroll
    for (int kt = 0; kt < NK32; ++kt) {
      const float* p = xs + kt * 32 + q * 8;
      const float2v r0 = *(const float2v*)(p);
      const float2v r1 = *(const float2v*)(p + 2);
      const float2v r2 = *(const float2v*)(p + 4);
      const float2v r3 = *(const float2v*)(p + 6);
      union { short8v s; unsigned u[4]; } fr;
      fr.u[0] = cvt_pk_bf16(r0[0], r0[1]);
      fr.u[1] = cvt_pk_bf16(r1[0], r1[1]);
      fr.u[2] = cvt_pk_bf16(r2[0], r2[1]);
      fr.u[3] = cvt_pk_bf16(r3[0], r3[1]);
      xF[kt] = fr.s;
    }
#pragma unroll
    for (int T = 0; T < 4; ++T) {
      float4v g4 = binit[T];
#pragma unroll
      for (int kt = 0; kt < NK32; ++kt) g4 = mfma32(wfx[T][kt], xF[kt], g4);
      gxA[T] = g4;
    }
    // raw x[1] from slot 1
    const float* xs1 = xbuf + FPS + c * D;
#pragma unroll
    for (int kt = 0; kt < NK32; ++kt) {
      const float* p = xs1 + kt * 32 + q * 8;
      nxr[kt][0] = *(const float2v*)(p);
      nxr[kt][1] = *(const float2v*)(p + 2);
      nxr[kt][2] = *(const float2v*)(p + 4);
      nxr[kt][3] = *(const float2v*)(p + 6);
    }
    LGKM0;  // prologue slot-0/1 reads complete before STEP(0) restages slot 0
  }

  // one step; i = t&3 compile-time. Entry: gc = gates(t), nxr = raw x[t+1].
  // Produces gn = gates(t+1), nxr = raw x[t+2].
  auto STEP = [&](int t, int i, float4v (&gc)[4], float4v (&gn)[4]) {
    const int pb = i & 1;
    const bool mystage = ((i & 1) == wid);        // stage x[t+4] -> slot i&3
    const bool mydrain = ((i & 1) == (wid ^ 1));  // drain stage from step t-1
    // on-chain: h of step t-1 (all 32 units)
    const short8v hB = *(const short8v*)(Hu + pb * HBUF + c * HSTR + q * 8);
    // staging: slot i&3 (x[t] there is dead since step t-2's raw reads)
    if (mystage && t + 4 < T_STEPS) stageslot(xbuf + (i & 3) * FPS);
    // issue raw reads of x[t+2] (slot staged t-2, drained/published end t-1);
    // latency hides under production + trans below.
    float2v nx2[NK32][4];
    {
      const float* xs2 = xbuf + ((i + 2) & 3) * FPS + c * D;
#pragma unroll
      for (int kt = 0; kt < NK32; ++kt) {
        const float* p = xs2 + kt * 32 + q * 8;
        nx2[kt][0] = *(const float2v*)(p);
        nx2[kt][1] = *(const float2v*)(p + 2);
        nx2[kt][2] = *(const float2v*)(p + 4);
        nx2[kt][3] = *(const float2v*)(p + 6);
      }
    }
    // convert prefetched raw x[t+1] -> frags (no LDS latency here)
    short8v xN[NK32];
#pragma unroll
    for (int kt = 0; kt < NK32; ++kt) {
      union { short8v s; unsigned u[4]; } fr;
      fr.u[0] = cvt_pk_bf16(nxr[kt][0][0], nxr[kt][0][1]);
      fr.u[1] = cvt_pk_bf16(nxr[kt][1][0], nxr[kt][1][1]);
      fr.u[2] = cvt_pk_bf16(nxr[kt][2][0], nxr[kt][2][1]);
      fr.u[3] = cvt_pk_bf16(nxr[kt][3][0], nxr[kt][3][1]);
      xN[kt] = fr.s;
    }
    // production MFMAs -> gates(t+1)
#pragma unroll
    for (int T = 0; T < 4; ++T) {
      float4v g4 = binit[T];
#pragma unroll
      for (int kt = 0; kt < NK32; ++kt) g4 = mfma32(wfx[T][kt], xN[kt], g4);
      gn[T] = g4;
    }
    // on-chain: 4 h-MFMAs + lean trans (prioritized)
    __builtin_amdgcn_s_setprio(1);
    float hv[4];
#pragma unroll
    for (int T = 0; T < 4; ++T) {
      const float4v acc = mfma32(wfh[T], hB, gc[T]);
      const float iv = sigm_(acc[0]);
      const float fv = sigm_(acc[1]);
      const float gv = tanh_(acc[2]);
      const float ov = sigm_(acc[3]);
      const float cv = fv * cst[T] + iv * gv;
      cst[T] = cv;
      hv[T] = ov * tanh_(cv);
    }
    uint2v hp;
    hp[0] = cvt_pk_bf16(hv[0], hv[1]);
    hp[1] = cvt_pk_bf16(hv[2], hv[3]);
    *(uint2v*)(Hu + (1 - pb) * HBUF + c * HSTR + wid * 16 + q * 4) = hp;
    __builtin_amdgcn_s_setprio(0);
    // hand nx2 -> nxr for next step
#pragma unroll
    for (int kt = 0; kt < NK32; ++kt) {
      nxr[kt][0] = nx2[kt][0];
      nxr[kt][1] = nx2[kt][1];
      nxr[kt][2] = nx2[kt][2];
      nxr[kt][3] = nx2[kt][3];
    }
    LGKM0;                 // h write + raw reads drained
    if (mydrain) { VM0; }  // drain own stage issued at step t-1 (1 outstanding)
    __builtin_amdgcn_s_barrier();
  };

  for (int tb = 0; tb < T_STEPS; tb += 8) {
    STEP(tb + 0, 0, gxA, gxB);
    STEP(tb + 1, 1, gxB, gxA);
    STEP(tb + 2, 2, gxA, gxB);
    STEP(tb + 3, 3, gxB, gxA);
    STEP(tb + 4, 0, gxA, gxB);
    STEP(tb + 5, 1, gxB, gxA);
    STEP(tb + 6, 2, gxA, gxB);
    STEP(tb + 7, 3, gxB, gxA);
  }

  // epilogue: h[255] in H buffer 0 (t=255 odd writes pb^1=0)
  {
    const short8v hB = *(const short8v*)(Hu + c * HSTR + q * 8);
    const float* wor = Wo + (16 * wid + c) * 32;
    short8v w8;
#pragma unroll
    for (int e = 0; e < 8; ++e) w8[e] = bf16r(wor[q * 8 + e]);
    float4v o4 = {0.0f, 0.0f, 0.0f, 0.0f};
    o4 = mfma32(w8, hB, o4);
    float4v res;
#pragma unroll
    for (int r = 0; r < 4; ++r)
      res[r] = fmaxf(o4[r] + bo[16 * wid + q * 4 + r], 0.0f);
    *(float4v*)(outf + (size_t)(n0 + c) * 32 + 16 * wid + q * 4) = res;
  }
}

// lf path: 8 samples per block, 128 threads.
__device__ void lf8(const float* __restrict__ l, const float* __restrict__ lW1,
                    const float* __restrict__ lb1,
                    const float* __restrict__ lW2,
                    const float* __restrict__ lb2, float* __restrict__ lf,
                    int n0, char* smem) {
  float* lsh = (float*)smem;          // 8*768 floats
  float* h1sh = lsh + 8 * 768;        // 8*128 floats
  const int tid = threadIdx.x;

  {
    const float4v* src = (const float4v*)(l + (size_t)n0 * 768);
    float4v* dst = (float4v*)lsh;
#pragma unroll
    for (int i = 0; i < 12; ++i) dst[tid + i * 128] = src[tid + i * 128];
  }
  __syncthreads();

  {  // phase 1: h1[8][128]; thread = one u of 128, all 8 samples
    const int u = tid;
    float acc[8];
#pragma unroll
    for (int i = 0; i < 8; ++i) acc[i] = 0.0f;
    const float4v* wrow = (const float4v*)(lW1 + u * 768);
    for (int k4 = 0; k4 < 192; ++k4) {
      const float4v w = wrow[k4];
#pragma unroll
      for (int i = 0; i < 8; ++i) {
        const float4v xv = ((const float4v*)(lsh + i * 768))[k4];
        acc[i] += w[0] * xv[0] + w[1] * xv[1] + w[2] * xv[2] + w[3] * xv[3];
      }
    }
    const float b = lb1[u];
#pragma unroll
    for (int i = 0; i < 8; ++i)
      h1sh[i * 128 + u] = fmaxf(acc[i] + b, 0.0f);
  }
  __syncthreads();

  {  // phase 2: lf[8][32]
    const int u2 = tid & 31;
    const int sg = tid >> 5;  // 0..3
    float acc0 = 0.0f, acc1 = 0.0f;
    const float4v* w2 = (const float4v*)(lW2 + u2 * 128);
#pragma unroll
    for (int k4 = 0; k4 < 32; ++k4) {
      const float4v w = w2[k4];
      const float4v xa = ((const float4v*)(h1sh + sg * 128))[k4];
      const float4v xb = ((const float4v*)(h1sh + (sg + 4) * 128))[k4];
      acc0 += w[0] * xa[0] + w[1] * xa[1] + w[2] * xa[2] + w[3] * xa[3];
      acc1 += w[0] * xb[0] + w[1] * xb[1] + w[2] * xb[2] + w[3] * xb[3];
    }
    const float b2 = lb2[u2];
    lf[(size_t)(n0 + sg) * 32 + u2] = fmaxf(acc0 + b2, 0.0f);
    lf[(size_t)(n0 + sg + 4) * 32 + u2] = fmaxf(acc1 + b2, 0.0f);
  }
}

__global__ __launch_bounds__(128, 2) void front_kernel(
    const float* __restrict__ a, const float* __restrict__ v,
    const float* __restrict__ aWih, const float* __restrict__ aWhh,
    const float* __restrict__ abih, const float* __restrict__ abhh,
    const float* __restrict__ aWo, const float* __restrict__ abo,
    const float* __restrict__ vWih, const float* __restrict__ vWhh,
    const float* __restrict__ vbih, const float* __restrict__ vbhh,
    const float* __restrict__ vWo, const float* __restrict__ vbo,
    const float* __restrict__ l, const float* __restrict__ lW1,
    const float* __restrict__ lb1, const float* __restrict__ lW2,
    const float* __restrict__ lb2, float* __restrict__ lfw,
    float* __restrict__ afw, float* __restrict__ vfw) {
  __shared__ __align__(16) char smem[SMEM_BYTES];
  const int b = blockIdx.x;
  if (b < 512) {
    lf8(l, lW1, lb1, lW2, lb2, lfw, b * 8, smem);
  } else if (b < 768) {
    lstm2w<74, 3>(a, aWih, aWhh, abih, abhh, aWo, abo, afw, (b - 512) * 16,
                  smem);
  } else {
    lstm2w<47, 2>(v, vWih, vWhh, vbih, vbhh, vWo, vbo, vfw, (b - 768) * 16,
                  smem);
  }
}

// ---------------------------------------------------------------------------
// Transformer block + post-fusion head. 32 lanes/sample, 8 samples/block.
// ---------------------------------------------------------------------------
__global__ __launch_bounds__(256) void head_kernel(
    const float* __restrict__ lf, const float* __restrict__ af,
    const float* __restrict__ vf, const float* __restrict__ Wq,
    const float* __restrict__ bq, const float* __restrict__ Wk,
    const float* __restrict__ bk, const float* __restrict__ Wv,
    const float* __restrict__ bv, const float* __restrict__ Wz,
    const float* __restrict__ bz, const float* __restrict__ Wff,
    const float* __restrict__ bff, const float* __restrict__ g1,
    const float* __restrict__ be1, const float* __restrict__ g2,
    const float* __restrict__ be2, const float* __restrict__ Wp1,
    const float* __restrict__ bp1, const float* __restrict__ Wp2,
    const float* __restrict__ bp2, float* __restrict__ out) {
  __shared__ float shA[8][3][33];
  __shared__ float shB[8][3][33];
  const int tid = threadIdx.x;
  const int j = tid & 31;
  const int slot = tid >> 5;
  const int n = blockIdx.x * 8 + slot;
  const size_t off = (size_t)n * 32 + j;

  const float x0 = lf[off], x1 = af[off], x2 = vf[off];

  auto ln3 = [&](float a0, float a1, float a2, const float* g,
                 const float* be, float* o) {
    float s = a0 + a1 + a2;
    s += __shfl_xor(s, 1); s += __shfl_xor(s, 2); s += __shfl_xor(s, 4);
    s += __shfl_xor(s, 8); s += __shfl_xor(s, 16);
    const float mu = s * (1.0f / 96.0f);
    const float d0 = a0 - mu, d1 = a1 - mu, d2 = a2 - mu;
    float ss = d0 * d0 + d1 * d1 + d2 * d2;
    ss += __shfl_xor(ss, 1); ss += __shfl_xor(ss, 2); ss += __shfl_xor(ss, 4);
    ss += __shfl_xor(ss, 8); ss += __shfl_xor(ss, 16);
    const float rs = rsqrtf(ss * (1.0f / 96.0f) + 1e-5f);
    o[0] = d0 * rs * g[j] + be[j];
    o[1] = d1 * rs * g[32 + j] + be[32 + j];
    o[2] = d2 * rs * g[64 + j] + be[64 + j];
  };

  float z[3];
  ln3(x0, x1, x2, g1, be1, z);
  shA[slot][0][j] = z[0]; shA[slot][1][j] = z[1]; shA[slot][2][j] = z[2];
  __syncthreads();

  float qv[3], kv[3], vv[3];
  {
    const float bqj = bq[j], bkj = bk[j], bvj = bv[j];
    qv[0] = bqj; qv[1] = bqj; qv[2] = bqj;
    kv[0] = bkj; kv[1] = bkj; kv[2] = bkj;
    vv[0] = bvj; vv[1] = bvj; vv[2] = bvj;
    const float* wqr = Wq + j * 32;
    const float* wkr = Wk + j * 32;
    const float* wvr = Wv + j * 32;
#pragma unroll 8
    for (int k = 0; k < 32; ++k) {
      const float zz0 = shA[slot][0][k], zz1 = shA[slot][1][k],
                  zz2 = shA[slot][2][k];
      const float wq = wqr[k], wk_ = wkr[k], wv_ = wvr[k];
      qv[0] += wq * zz0;  qv[1] += wq * zz1;  qv[2] += wq * zz2;
      kv[0] += wk_ * zz0; kv[1] += wk_ * zz1; kv[2] += wk_ * zz2;
      vv[0] += wv_ * zz0; vv[1] += wv_ * zz1; vv[2] += wv_ * zz2;
    }
  }

  float at[3][3];
#pragma unroll
  for (int s = 0; s < 3; ++s)
#pragma unroll
    for (int t2 = 0; t2 < 3; ++t2) {
      float p = qv[s] * kv[t2];
      p += __shfl_xor(p, 1); p += __shfl_xor(p, 2); p += __shfl_xor(p, 4);
      at[s][t2] = p;
    }
#pragma unroll
  for (int s = 0; s < 3; ++s) {
    const float m = fmaxf(fmaxf(at[s][0], at[s][1]), at[s][2]);
    const float e0 = __expf(at[s][0] - m), e1 = __expf(at[s][1] - m),
                e2 = __expf(at[s][2] - m);
    const float sc = 0.35355339059327373f * __fdividef(1.0f, e0 + e1 + e2);
    at[s][0] = e0 * sc; at[s][1] = e1 * sc; at[s][2] = e2 * sc;
  }
  float zc[3];
#pragma unroll
  for (int s = 0; s < 3; ++s)
    zc[s] = at[s][0] * vv[0] + at[s][1] * vv[1] + at[s][2] * vv[2];
  shB[slot][0][j] = zc[0]; shB[slot][1][j] = zc[1]; shB[slot][2][j] = zc[2];
  __syncthreads();

  const float bzj = bz[j];
  float z2a[3] = {bzj + x0, bzj + x1, bzj + x2};
  {
    const float* wzr = Wz + j * 32;
#pragma unroll 8
    for (int k = 0; k < 32; ++k) {
      const float w = wzr[k];
      z2a[0] += w * shB[slot][0][k];
      z2a[1] += w * shB[slot][1][k];
      z2a[2] += w * shB[slot][2][k];
    }
  }

  float zn[3];
  ln3(z2a[0], z2a[1], z2a[2], g2, be2, zn);
  shA[slot][0][j] = zn[0]; shA[slot][1][j] = zn[1]; shA[slot][2][j] = zn[2];
  __syncthreads();

  const float bffj = bff[j];
  float Za[3] = {bffj + z2a[0], bffj + z2a[1], bffj + z2a[2]};
  {
    const float* wfr = Wff + j * 32;
#pragma unroll 8
    for (int k = 0; k < 32; ++k) {
      const float w = wfr[k];
      Za[0] += w * shA[slot][0][k];
      Za[1] += w * shA[slot][1][k];
      Za[2] += w * shA[slot][2][k];
    }
  }
  shB[slot][0][j] = Za[0]; shB[slot][1][j] = Za[1]; shB[slot][2][j] = Za[2];
  __syncthreads();

  float p = bp1[j];
  {
    const float* wpr = Wp1 + j * 96;
#pragma unroll
    for (int s = 0; s < 3; ++s)
#pragma unroll 8
      for (int k = 0; k < 32; ++k) p += wpr[s * 32 + k] * shB[slot][s][k];
  }
  p = fmaxf(p, 0.0f);
  float l0 = Wp2[j] * p, l1 = Wp2[32 + j] * p;
  l0 += __shfl_xor(l0, 1); l0 += __shfl_xor(l0, 2); l0 += __shfl_xor(l0, 4);
  l0 += __shfl_xor(l0, 8); l0 += __shfl_xor(l0, 16);
  l1 += __shfl_xor(l1, 1); l1 += __shfl_xor(l1, 2); l1 += __shfl_xor(l1, 4);
  l1 += __shfl_xor(l1, 8); l1 += __shfl_xor(l1, 16);
  l0 += bp2[0]; l1 += bp2[1];
  const float mx = fmaxf(l0, l1);
  const float e0 = __expf(l0 - mx), e1 = __expf(l1 - mx);
  const float inv = __fdividef(1.0f, e0 + e1);
  if (j == 0) {
    out[(size_t)n * 2 + 0] = e0 * inv;
    out[(size_t)n * 2 + 1] = e1 * inv;
  }
}

// ---------------------------------------------------------------------------
extern "C" void kernel_launch(void* const* d_in, const int* in_sizes, int n_in,
                              void* d_out, int out_size, void* d_ws,
                              size_t ws_size, hipStream_t stream) {
  const float* l    = (const float*)d_in[0];
  const float* a    = (const float*)d_in[1];
  const float* v    = (const float*)d_in[2];
  const float* lW1  = (const float*)d_in[3];
  const float* lb1  = (const float*)d_in[4];
  const float* lW2  = (const float*)d_in[5];
  const float* lb2  = (const float*)d_in[6];
  const float* aWih = (const float*)d_in[7];
  const float* aWhh = (const float*)d_in[8];
  const float* abih = (const float*)d_in[9];
  const float* abhh = (const float*)d_in[10];
  const float* aWo  = (const float*)d_in[11];
  const float* abo  = (const float*)d_in[12];
  const float* vWih = (const float*)d_in[13];
  const float* vWhh = (const float*)d_in[14];
  const float* vbih = (const float*)d_in[15];
  const float* vbhh = (const float*)d_in[16];
  const float* vWo  = (const float*)d_in[17];
  const float* vbo  = (const float*)d_in[18];
  const float* Wq   = (const float*)d_in[19];
  const float* bq   = (const float*)d_in[20];
  const float* Wk   = (const float*)d_in[21];
  const float* bk   = (const float*)d_in[22];
  const float* Wv   = (const float*)d_in[23];
  const float* bv   = (const float*)d_in[24];
  const float* Wz   = (const float*)d_in[25];
  const float* bz   = (const float*)d_in[26];
  const float* Wff  = (const float*)d_in[27];
  const float* bff  = (const float*)d_in[28];
  const float* g1   = (const float*)d_in[29];
  const float* be1  = (const float*)d_in[30];
  const float* g2   = (const float*)d_in[31];
  const float* be2  = (const float*)d_in[32];
  const float* Wp1  = (const float*)d_in[33];
  const float* bp1  = (const float*)d_in[34];
  const float* Wp2  = (const float*)d_in[35];
  const float* bp2  = (const float*)d_in[36];

  float* out = (float*)d_out;
  float* ws = (float*)d_ws;
  float* lfw = ws;
  float* afw = ws + 4096 * 32;
  float* vfw = ws + 2 * 4096 * 32;

  hipLaunchKernelGGL(front_kernel, dim3(1024), dim3(128), 0, stream, a, v,
                     aWih, aWhh, abih, abhh, aWo, abo, vWih, vWhh, vbih,
                     vbhh, vWo, vbo, l, lW1, lb1, lW2, lb2, lfw, afw, vfw);
  hipLaunchKernelGGL(head_kernel, dim3(512), dim3(256), 0, stream, lfw, afw,
                     vfw, Wq, bq, Wk, bk, Wv, bv, Wz, bz, Wff, bff, g1, be1,
                     g2, be2, Wp1, bp1, Wp2, bp2, out);
}